// Round 1
// baseline (916.770 us; speedup 1.0000x reference)
//
#include <hip/hip_runtime.h>
#include <hip/hip_bf16.h>
#include <math.h>

#define NN 50000
#define EE 800000
#define HH 128
#define FF 128
#define GG 50
#define LL 6
#define H2D 64
#define OUT_DIM 12
#define NK 4096          // nearest-neighbor table intervals; knots 0..NK (4097)
#define NBLK 782         // ceil(NN/64)
#define SB 196           // scan blocks: ceil(NN/256)
#define NBUK 196         // scatter buckets: 256 nodes each

typedef __bf16 bf16;
typedef __attribute__((ext_vector_type(8))) __bf16 bf16x8;
typedef __attribute__((ext_vector_type(4))) __bf16 bf16x4;
typedef __attribute__((ext_vector_type(4))) float f32x4;
typedef __attribute__((ext_vector_type(4))) unsigned u32x4;

#define DEV __device__ __forceinline__

// fast shifted-softplus: hw v_exp/v_log, err ~1e-6 << bf16 rounding
DEV float sspf(float x) {
    return fmaxf(x, 0.f) + __logf(1.f + __expf(-fabsf(x))) - 0.69314718055994531f;
}

DEV f32x4 mfma16(bf16x8 a, bf16x8 b, f32x4 c) {
    return __builtin_amdgcn_mfma_f32_16x16x32_bf16(a, b, c, 0, 0, 0);
}

DEV float blo(unsigned u) { return __uint_as_float(u << 16); }
DEV float bhi(unsigned u) { return __uint_as_float(u & 0xffff0000u); }

// -------- prep: transpose all weights to [n][k] bf16 (+ zero hist) -----------
struct PrepArgs {
    const float *conv1_w, *conv2_w, *int_lin_w, *mlp_w1, *mlp_w2, *lin1_w, *lin2_w;
    bf16 *c1t, *c2t, *ilt, *w1t, *w2t, *l1t, *l2t;
    int* hist;
};

__global__ void prep_kernel(PrepArgs p) {
    int j = blockIdx.x;
    // fused hist zeroing (grid-stride over all 32 blocks)
    for (int i = blockIdx.x * 256 + threadIdx.x; i < NN; i += 32 * 256) p.hist[i] = 0;
    const float* src = nullptr; bf16* dst = nullptr; int R = 0, C = 0, K = 0;
    if (j < 30) {
        int l = j / 5, m = j % 5;
        switch (m) {
            case 0: src = p.conv1_w + l * HH * FF;   dst = p.c1t + l * FF * HH;  R = HH; C = FF; K = HH; break;
            case 1: src = p.conv2_w + l * FF * HH;   dst = p.c2t + l * HH * FF;  R = FF; C = HH; K = FF; break;
            case 2: src = p.int_lin_w + l * HH * HH; dst = p.ilt + l * HH * HH;  R = HH; C = HH; K = HH; break;
            case 3: src = p.mlp_w1 + l * GG * FF;    dst = p.w1t + l * FF * 64;  R = GG; C = FF; K = 64; break;
            case 4: src = p.mlp_w2 + l * FF * FF;    dst = p.w2t + l * FF * FF;  R = FF; C = FF; K = FF; break;
        }
    } else if (j == 30) { src = p.lin1_w; dst = p.l1t; R = HH;  C = H2D; K = HH; }
    else                { src = p.lin2_w; dst = p.l2t; R = H2D; C = H2D; K = H2D; }
    int total = C * K;
    for (int idx = threadIdx.x; idx < total; idx += blockDim.x) {
        int c = idx / K, r = idx - c * K;
        dst[idx] = (r < R) ? (bf16)src[r * C + c] : (bf16)0.f;
    }
}

// -------- table build via MFMA: T[l][r][:] = (ssp(g(d)@W1+b1)@W2+b2)*C(d) ----
__global__ __launch_bounds__(256) void table_kernel(const bf16* __restrict__ w1t,
                                                    const bf16* __restrict__ w2t,
                                                    const float* __restrict__ mlp_b1,
                                                    const float* __restrict__ mlp_b2,
                                                    bf16* __restrict__ tab) {
    __shared__ bf16 sW1[128 * 72];
    __shared__ bf16 sW2[128 * 136];
    __shared__ bf16 sT1[64 * 136];
    int tid = threadIdx.x;
    int l = blockIdx.x / 65, rb = blockIdx.x % 65;
    const bf16* W1 = w1t + (size_t)l * 128 * 64;
    const bf16* W2 = w2t + (size_t)l * 128 * 128;
    for (int idx = tid * 8; idx < 128 * 64; idx += 2048) {
        int n = idx >> 6, k = idx & 63;
        *(bf16x8*)&sW1[n * 72 + k] = *(const bf16x8*)(W1 + idx);
    }
    for (int idx = tid * 8; idx < 128 * 128; idx += 2048) {
        int n = idx >> 7, k = idx & 127;
        *(bf16x8*)&sW2[n * 136 + k] = *(const bf16x8*)(W2 + idx);
    }
    int w = tid >> 6, lane = tid & 63, ln = lane & 15, kg = lane >> 4;
    int rowt = rb * 64 + w * 16;
    float d1 = (float)min(rowt + ln, NK) * (10.f / NK);
    const float step = 10.f / 49.f;
    const float coeff = -0.5f / (step * step);
    __syncthreads();
    // GEMM1: in-register gaussian basis @ W1
    f32x4 acc[8] = {};
#pragma unroll
    for (int k0 = 0; k0 < 64; k0 += 32) {
        bf16x8 a;
#pragma unroll
        for (int jj = 0; jj < 8; jj++) {
            int g = k0 + kg * 8 + jj;
            float diff = d1 - g * step;
            float v = (g < GG) ? __expf(coeff * diff * diff) : 0.f;
            a[jj] = (bf16)v;
        }
#pragma unroll
        for (int t = 0; t < 8; t++) {
            bf16x8 b = *(const bf16x8*)&sW1[(t * 16 + ln) * 72 + k0 + kg * 8];
            acc[t] = mfma16(a, b, acc[t]);
        }
    }
    const float* b1 = mlp_b1 + l * FF;
#pragma unroll
    for (int t = 0; t < 8; t++) {
        int colt = t * 16 + ln;
        float bb = b1[colt];
#pragma unroll
        for (int r = 0; r < 4; r++)
            sT1[(w * 16 + kg * 4 + r) * 136 + colt] = (bf16)sspf(acc[t][r] + bb);
    }
    __syncthreads();
    f32x4 acc2[8] = {};
#pragma unroll
    for (int k0 = 0; k0 < 128; k0 += 32) {
        bf16x8 a = *(const bf16x8*)&sT1[(w * 16 + ln) * 136 + k0 + kg * 8];
#pragma unroll
        for (int t = 0; t < 8; t++) {
            bf16x8 b = *(const bf16x8*)&sW2[(t * 16 + ln) * 136 + k0 + kg * 8];
            acc2[t] = mfma16(a, b, acc2[t]);
        }
    }
    const float* b2 = mlp_b2 + l * FF;
    float Cw[4]; int rrow[4];
#pragma unroll
    for (int r = 0; r < 4; r++) {
        int rr = rowt + kg * 4 + r;
        rrow[r] = rr;
        float dd = (float)min(rr, NK) * (10.f / NK);
        Cw[r] = 0.5f * (cosf(dd * 0.31415926535897932f) + 1.f);
    }
#pragma unroll
    for (int t = 0; t < 8; t++) {
        int colt = t * 16 + ln;
        float bb = b2[colt];
#pragma unroll
        for (int r = 0; r < 4; r++) {
            if (rrow[r] <= NK)
                tab[((size_t)l * (NK + 1) + rrow[r]) * FF + colt] = (bf16)((acc2[t][r] + bb) * Cw[r]);
        }
    }
}

// -------- edge sort by dst: histogram / hierarchical scan --------------------
__global__ void hist_kernel(const int* __restrict__ eidx, int* __restrict__ hist) {
    int e = blockIdx.x * 256 + threadIdx.x;
    if (e < EE) atomicAdd(&hist[eidx[EE + e]], 1);
}

__global__ __launch_bounds__(256) void scanA_kernel(const int* __restrict__ hist,
                                                    int* __restrict__ bsum) {
    __shared__ int red[256];
    int t = threadIdx.x;
    int i = blockIdx.x * 256 + t;
    int v = (i < NN) ? hist[i] : 0;
    red[t] = v;
    __syncthreads();
    for (int off = 128; off > 0; off >>= 1) {
        if (t < off) red[t] += red[t + off];
        __syncthreads();
    }
    if (t == 0) bsum[blockIdx.x] = red[0];
}

__global__ __launch_bounds__(256) void scanB_kernel(int* __restrict__ bsum) {
    __shared__ int buf[256];
    int t = threadIdx.x;
    int v = (t < SB) ? bsum[t] : 0;
    buf[t] = v;
    __syncthreads();
    for (int off = 1; off < 256; off <<= 1) {
        int y = (t >= off) ? buf[t - off] : 0;
        __syncthreads();
        buf[t] += y;
        __syncthreads();
    }
    if (t < SB) bsum[t] = buf[t] - v;   // exclusive
}

__global__ __launch_bounds__(256) void scanC_kernel(const int* __restrict__ hist,
                                                    const int* __restrict__ bsum,
                                                    int* __restrict__ rs,
                                                    int* __restrict__ bucket_cur) {
    __shared__ int buf[256];
    int t = threadIdx.x;
    int i = blockIdx.x * 256 + t;
    int v = (i < NN) ? hist[i] : 0;
    buf[t] = v;
    __syncthreads();
    for (int off = 1; off < 256; off <<= 1) {
        int y = (t >= off) ? buf[t - off] : 0;
        __syncthreads();
        buf[t] += y;
        __syncthreads();
    }
    if (i < NN) {
        int ex = buf[t] - v + bsum[blockIdx.x];
        rs[i] = ex;
        if ((i & 255) == 0) bucket_cur[i >> 8] = ex;   // bucket base (fused bukinit)
    }
}

// -------- bucketed two-pass scatter (kills 64B-line write amplification) -----
// pass 1: 196 blocks x 4096 edges -> bucket-grouped tmp (int2: packed, dst)
__global__ __launch_bounds__(256) void scat1_kernel(const float* __restrict__ eattr,
                                                    const int* __restrict__ eidx,
                                                    int* __restrict__ bucket_cur,
                                                    int2* __restrict__ tmp8) {
    __shared__ int cnt[NBUK];
    __shared__ int res[NBUK];
    int t = threadIdx.x;
    for (int i = t; i < NBUK; i += 256) cnt[i] = 0;
    __syncthreads();
    int e0 = blockIdx.x * 4096;
    int pv[16], dd[16], bk[16];
#pragma unroll
    for (int i = 0; i < 16; i++) {
        int e = e0 + i * 256 + t;
        if (e < EE) {
            int d = eidx[EE + e];
            int k = (int)(eattr[e] * ((float)NK / 10.f) + 0.5f);
            k = min(k, NK);
            pv[i] = k | (eidx[e] << 13);
            dd[i] = d;
            bk[i] = d >> 8;
            atomicAdd(&cnt[bk[i]], 1);
        } else bk[i] = -1;
    }
    __syncthreads();
    for (int i = t; i < NBUK; i += 256) {
        int c = cnt[i];
        res[i] = (c > 0) ? atomicAdd(&bucket_cur[i], c) : 0;
        cnt[i] = 0;          // reuse as local rank counter
    }
    __syncthreads();
#pragma unroll
    for (int i = 0; i < 16; i++) {
        if (bk[i] >= 0) {
            int rank = atomicAdd(&cnt[bk[i]], 1);
            int2 v; v.x = pv[i]; v.y = dd[i];
            tmp8[res[bk[i]] + rank] = v;
        }
    }
}

// pass 2: one block per bucket -> final dst-sorted es (dense 16KB window)
__global__ __launch_bounds__(256) void scat2_kernel(const int* __restrict__ rs,
                                                    const int2* __restrict__ tmp8,
                                                    int* __restrict__ es) {
    __shared__ int off[256];
    __shared__ int loc[256];
    int b = blockIdx.x, t = threadIdx.x;
    int nb0 = b * 256;
    int nnb = min(256, NN - nb0);          // nodes in this bucket
    int base = rs[nb0];
    int end = (nb0 + 256 < NN) ? rs[nb0 + 256] : EE;
    loc[t] = 0;
    if (t < nnb) off[t] = rs[nb0 + t] - base;
    __syncthreads();
    for (int e = base + t; e < end; e += 256) {
        int2 v = tmp8[e];
        int nl = v.y - nb0;
        int rank = atomicAdd(&loc[nl], 1);
        es[base + off[nl] + rank] = v.x;
    }
}

// -------- xf0: hb = embedding[x_atoms]; xf = hb @ conv1_w (fused, layer 0) ---
__global__ __launch_bounds__(256) void xf0_kernel(const int* __restrict__ x_atoms,
                                                  const float* __restrict__ emb,
                                                  const bf16* __restrict__ c1t,
                                                  bf16* __restrict__ hb,
                                                  bf16* __restrict__ xf) {
    __shared__ bf16 sB[128 * 136];
    int tid = threadIdx.x;
    for (int idx = tid * 8; idx < 128 * 128; idx += 2048) {
        int n = idx >> 7, k = idx & 127;
        *(bf16x8*)&sB[n * 136 + k] = *(const bf16x8*)(c1t + idx);
    }
    int w = tid >> 6, lane = tid & 63, ln = lane & 15, kg = lane >> 4;
    int rowt = blockIdx.x * 64 + w * 16;
    int nrow = rowt + ln;
    int arow = min(nrow, NN - 1);
    bool rowok = nrow < NN;
    int atom = x_atoms[arow];
    __syncthreads();
    f32x4 acc[8] = {};
#pragma unroll
    for (int k0 = 0; k0 < 128; k0 += 32) {
        const float* ep = emb + (size_t)atom * HH + k0 + kg * 8;
        f32x4 u0 = *(const f32x4*)ep;
        f32x4 u1 = *(const f32x4*)(ep + 4);
        bf16x8 a;
#pragma unroll
        for (int q = 0; q < 4; q++) { a[q] = (bf16)u0[q]; a[q + 4] = (bf16)u1[q]; }
        if (rowok) *(bf16x8*)(hb + (size_t)nrow * HH + k0 + kg * 8) = a;
#pragma unroll
        for (int t = 0; t < 8; t++) {
            bf16x8 b = *(const bf16x8*)&sB[(t * 16 + ln) * 136 + k0 + kg * 8];
            acc[t] = mfma16(a, b, acc[t]);
        }
    }
#pragma unroll
    for (int t = 0; t < 8; t++) {
        int colt = t * 16 + ln;
#pragma unroll
        for (int r = 0; r < 4; r++) {
            int orow = rowt + kg * 4 + r;
            if (orow < NN) xf[orow * FF + colt] = (bf16)acc[t][r];
        }
    }
}

// -------- edge kernel: CSR, one wave/node, nearest-knot ----------------------
// Restructured for MLP: each quarter handles 2 edges/iter (8 edges/wave-iter);
// all 4 dwordx4 loads issue before any FMA consumes -> deeper in-flight queue.
__global__ __launch_bounds__(256) void edge_kernel(const int* __restrict__ es,
                                                   const int* __restrict__ rs,
                                                   const int* __restrict__ hist,
                                                   const bf16* __restrict__ xf,
                                                   const bf16* __restrict__ tab,
                                                   bf16* __restrict__ aggb) {
    int tid = threadIdx.x;
    int w = tid >> 6, lane = tid & 63;
    int q = lane >> 4, cl = lane & 15;      // quarter q; lane covers ch [8cl,8cl+8)
    int n = blockIdx.x * 4 + w;
    int start = rs[n], deg = hist[n];
    float a0 = 0.f, a1 = 0.f, a2 = 0.f, a3 = 0.f;
    float a4 = 0.f, a5 = 0.f, a6 = 0.f, a7 = 0.f;
    for (int base = 0; base < deg; base += 64) {
        int cnt = min(deg - base, 64);
        int pv = (lane < cnt) ? es[start + base + lane] : 0;
        int iters = (cnt + 7) >> 3;         // 8 edges per wave-iter
#pragma unroll 2
        for (int j = 0; j < iters; j++) {
            int j0 = 8 * j + q;             // quarter's first edge
            int j1 = j0 + 4;                // quarter's second edge
            bool va = j0 < cnt, vb = j1 < cnt;
            int v0 = __shfl(pv, j0);
            int v1 = __shfl(pv, j1);
            int ka = v0 & 8191, sa = v0 >> 13;
            int kb = v1 & 8191, sb1 = v1 >> 13;
            u32x4 tpa = *(const u32x4*)(tab + (size_t)ka * FF + 8 * cl);
            u32x4 xua = *(const u32x4*)(xf + (size_t)sa * FF + 8 * cl);
            u32x4 tpb = *(const u32x4*)(tab + (size_t)kb * FF + 8 * cl);
            u32x4 xub = *(const u32x4*)(xf + (size_t)sb1 * FF + 8 * cl);
            unsigned ta0 = va ? tpa.x : 0u;
            unsigned ta1 = va ? tpa.y : 0u;
            unsigned ta2 = va ? tpa.z : 0u;
            unsigned ta3 = va ? tpa.w : 0u;
            unsigned tb0 = vb ? tpb.x : 0u;
            unsigned tb1 = vb ? tpb.y : 0u;
            unsigned tb2 = vb ? tpb.z : 0u;
            unsigned tb3 = vb ? tpb.w : 0u;
            a0 = fmaf(blo(ta0), blo(xua.x), a0);
            a1 = fmaf(bhi(ta0), bhi(xua.x), a1);
            a2 = fmaf(blo(ta1), blo(xua.y), a2);
            a3 = fmaf(bhi(ta1), bhi(xua.y), a3);
            a4 = fmaf(blo(ta2), blo(xua.z), a4);
            a5 = fmaf(bhi(ta2), bhi(xua.z), a5);
            a6 = fmaf(blo(ta3), blo(xua.w), a6);
            a7 = fmaf(bhi(ta3), bhi(xua.w), a7);
            a0 = fmaf(blo(tb0), blo(xub.x), a0);
            a1 = fmaf(bhi(tb0), bhi(xub.x), a1);
            a2 = fmaf(blo(tb1), blo(xub.y), a2);
            a3 = fmaf(bhi(tb1), bhi(xub.y), a3);
            a4 = fmaf(blo(tb2), blo(xub.z), a4);
            a5 = fmaf(bhi(tb2), bhi(xub.z), a5);
            a6 = fmaf(blo(tb3), blo(xub.w), a6);
            a7 = fmaf(bhi(tb3), bhi(xub.w), a7);
        }
    }
    a0 += __shfl_xor(a0, 16); a0 += __shfl_xor(a0, 32);
    a1 += __shfl_xor(a1, 16); a1 += __shfl_xor(a1, 32);
    a2 += __shfl_xor(a2, 16); a2 += __shfl_xor(a2, 32);
    a3 += __shfl_xor(a3, 16); a3 += __shfl_xor(a3, 32);
    a4 += __shfl_xor(a4, 16); a4 += __shfl_xor(a4, 32);
    a5 += __shfl_xor(a5, 16); a5 += __shfl_xor(a5, 32);
    a6 += __shfl_xor(a6, 16); a6 += __shfl_xor(a6, 32);
    a7 += __shfl_xor(a7, 16); a7 += __shfl_xor(a7, 32);
    if (q == 0) {
        bf16x8 pk;
        pk[0] = (bf16)a0; pk[1] = (bf16)a1; pk[2] = (bf16)a2; pk[3] = (bf16)a3;
        pk[4] = (bf16)a4; pk[5] = (bf16)a5; pk[6] = (bf16)a6; pk[7] = (bf16)a7;
        *(bf16x8*)(aggb + (size_t)n * FF + 8 * cl) = pk;
    }
}

// -------- update: transposed-output GEMMs (thread = 1 node x 4-feat spans) ---
__global__ __launch_bounds__(256) void update_kernel(const bf16* __restrict__ aggb,
                                                     const bf16* __restrict__ c2t,
                                                     const float* __restrict__ c2b,
                                                     const bf16* __restrict__ ilt,
                                                     const float* __restrict__ ilb,
                                                     bf16* __restrict__ hb,
                                                     const bf16* __restrict__ c1n,
                                                     bf16* __restrict__ xf_out,
                                                     const bf16* __restrict__ l1t,
                                                     const float* __restrict__ l1b,
                                                     const bf16* __restrict__ l2t,
                                                     const float* __restrict__ l2b,
                                                     float* __restrict__ partial) {
    __shared__ bf16 sB[128 * 136];   // restaged per GEMM
    __shared__ bf16 sT[64 * 136];
    int tid = threadIdx.x;
    int w = tid >> 6, lane = tid & 63, ln = lane & 15, kg = lane >> 4;
    int rowt = blockIdx.x * 64 + w * 16;
    int nrow = rowt + ln;                 // this thread's node (transposed layout)
    int arow = min(nrow, NN - 1);
    bool rowok = nrow < NN;
    // prefetch residual h: node nrow, feats t*16+kg*4 .. +4
    bf16x4 hpre[8];
#pragma unroll
    for (int t = 0; t < 8; t++)
        hpre[t] = *(const bf16x4*)(hb + (size_t)arow * HH + t * 16 + kg * 4);
    for (int idx = tid * 8; idx < 128 * 128; idx += 2048) {
        int n = idx >> 7, k = idx & 127;
        *(bf16x8*)&sB[n * 136 + k] = *(const bf16x8*)(c2t + idx);
    }
    __syncthreads();
    // GEMM1 (Ct): out[feat][node] = conv2^T @ agg^T  (operand-swapped MFMA)
    f32x4 acc[8] = {};
#pragma unroll
    for (int k0 = 0; k0 < 128; k0 += 32) {
        bf16x8 bfrag = *(const bf16x8*)(aggb + (size_t)arow * FF + k0 + kg * 8);
#pragma unroll
        for (int t = 0; t < 8; t++) {
            bf16x8 afrag = *(const bf16x8*)&sB[(t * 16 + ln) * 136 + k0 + kg * 8];
            acc[t] = mfma16(afrag, bfrag, acc[t]);
        }
    }
    // epilogue1: thread holds feats t*16+kg*4+[0..4) of node nrow -> b64 LDS writes
#pragma unroll
    for (int t = 0; t < 8; t++) {
        f32x4 bb = *(const f32x4*)(c2b + t * 16 + kg * 4);
        bf16x4 pk;
#pragma unroll
        for (int r = 0; r < 4; r++) pk[r] = (bf16)sspf(acc[t][r] + bb[r]);
        *(bf16x4*)&sT[(w * 16 + ln) * 136 + t * 16 + kg * 4] = pk;
    }
    __syncthreads();
    for (int idx = tid * 8; idx < 128 * 128; idx += 2048) {
        int n = idx >> 7, k = idx & 127;
        *(bf16x8*)&sB[n * 136 + k] = *(const bf16x8*)(ilt + idx);
    }
    __syncthreads();
    f32x4 acc2[8] = {};
#pragma unroll
    for (int k0 = 0; k0 < 128; k0 += 32) {
        bf16x8 bfrag = *(const bf16x8*)&sT[(w * 16 + ln) * 136 + k0 + kg * 8];
#pragma unroll
        for (int t = 0; t < 8; t++) {
            bf16x8 afrag = *(const bf16x8*)&sB[(t * 16 + ln) * 136 + k0 + kg * 8];
            acc2[t] = mfma16(afrag, bfrag, acc2[t]);
        }
    }
    bool is_last = (c1n == nullptr);
    // epilogue2: residual add, vector stores (own sT rows only -> no barrier needed)
#pragma unroll
    for (int t = 0; t < 8; t++) {
        f32x4 bb = *(const f32x4*)(ilb + t * 16 + kg * 4);
        bf16x4 pk;
#pragma unroll
        for (int r = 0; r < 4; r++)
            pk[r] = (bf16)((float)hpre[t][r] + acc2[t][r] + bb[r]);
        if (rowok && !is_last) *(bf16x4*)(hb + (size_t)nrow * HH + t * 16 + kg * 4) = pk;
        *(bf16x4*)&sT[(w * 16 + ln) * 136 + t * 16 + kg * 4] = pk;
    }
    if (!is_last) {
        // fused next-layer xf = h_new @ conv1_next (same transposed form)
        __syncthreads();
        for (int idx = tid * 8; idx < 128 * 128; idx += 2048) {
            int n = idx >> 7, k = idx & 127;
            *(bf16x8*)&sB[n * 136 + k] = *(const bf16x8*)(c1n + idx);
        }
        __syncthreads();
        f32x4 acc3[8] = {};
#pragma unroll
        for (int k0 = 0; k0 < 128; k0 += 32) {
            bf16x8 bfrag = *(const bf16x8*)&sT[(w * 16 + ln) * 136 + k0 + kg * 8];
#pragma unroll
            for (int t = 0; t < 8; t++) {
                bf16x8 afrag = *(const bf16x8*)&sB[(t * 16 + ln) * 136 + k0 + kg * 8];
                acc3[t] = mfma16(afrag, bfrag, acc3[t]);
            }
        }
#pragma unroll
        for (int t = 0; t < 8; t++) {
            bf16x4 pk;
#pragma unroll
            for (int r = 0; r < 4; r++) pk[r] = (bf16)acc3[t][r];
            if (rowok) *(bf16x4*)(xf_out + (size_t)nrow * FF + t * 16 + kg * 4) = pk;
        }
    } else {
        // fused head: ssp(h@lin1+b)@lin2+b, per-block partial sum (runs once)
        __syncthreads();
        for (int idx = tid * 8; idx < 64 * 128; idx += 2048) {
            int n = idx >> 7, k = idx & 127;
            *(bf16x8*)&sB[n * 136 + k] = *(const bf16x8*)(l1t + idx);
        }
        __syncthreads();
        f32x4 acch[4] = {};
#pragma unroll
        for (int k0 = 0; k0 < 128; k0 += 32) {
            bf16x8 a = *(const bf16x8*)&sT[(w * 16 + ln) * 136 + k0 + kg * 8];
#pragma unroll
            for (int t = 0; t < 4; t++) {
                bf16x8 b = *(const bf16x8*)&sB[(t * 16 + ln) * 136 + k0 + kg * 8];
                acch[t] = mfma16(a, b, acch[t]);
            }
        }
#pragma unroll
        for (int t = 0; t < 4; t++) {
            int colt = t * 16 + ln;
            float bb = l1b[colt];
#pragma unroll
            for (int r = 0; r < 4; r++)
                sT[(w * 16 + kg * 4 + r) * 136 + colt] = (bf16)sspf(acch[t][r] + bb);
        }
        __syncthreads();
        for (int idx = tid * 8; idx < 64 * 64; idx += 2048) {
            int n = idx >> 6, k = idx & 63;
            *(bf16x8*)&sB[n * 136 + k] = *(const bf16x8*)(l2t + idx);
        }
        __syncthreads();
        f32x4 acc2h[4] = {};
#pragma unroll
        for (int k0 = 0; k0 < 64; k0 += 32) {
            bf16x8 a = *(const bf16x8*)&sT[(w * 16 + ln) * 136 + k0 + kg * 8];
#pragma unroll
            for (int t = 0; t < 4; t++) {
                bf16x8 b = *(const bf16x8*)&sB[(t * 16 + ln) * 136 + k0 + kg * 8];
                acc2h[t] = mfma16(a, b, acc2h[t]);
            }
        }
        __syncthreads();   // all sT reads done; reuse as f32 scratch
        float* sPart = (float*)sT;
#pragma unroll
        for (int t = 0; t < 4; t++) {
            int colt = t * 16 + ln;
            float bb = l2b[colt];
            float v = 0.f;
#pragma unroll
            for (int r = 0; r < 4; r++) {
                int orow = rowt + kg * 4 + r;
                if (orow < NN) v += acc2h[t][r] + bb;
            }
            v += __shfl_xor(v, 16);
            v += __shfl_xor(v, 32);
            if (kg == 0) sPart[w * 64 + colt] = v;
        }
        __syncthreads();
        if (tid < 64) {
            float s = sPart[tid] + sPart[64 + tid] + sPart[128 + tid] + sPart[192 + tid];
            partial[blockIdx.x * 64 + tid] = s;
        }
    }
}

// -------- finalA: one block per column, parallel reduce over 782 partials ----
__global__ __launch_bounds__(256) void finalA_kernel(const float* __restrict__ partial,
                                                     float* __restrict__ colsum) {
    __shared__ float red[256];
    int c = blockIdx.x, t = threadIdx.x;
    float s = 0.f;
    for (int b = t; b < NBLK; b += 256) s += partial[b * 64 + c];
    red[t] = s;
    __syncthreads();
    for (int off = 128; off > 0; off >>= 1) {
        if (t < off) red[t] += red[t + off];
        __syncthreads();
    }
    if (t == 0) colsum[c] = red[0];
}

// -------- finalB: readout GEMV (64x12, trivial) ------------------------------
__global__ __launch_bounds__(64) void finalB_kernel(const float* __restrict__ colsum,
                                                    const float* __restrict__ rw,
                                                    const float* __restrict__ rb,
                                                    float* __restrict__ out) {
    __shared__ float sv[64];
    int j = threadIdx.x;
    sv[j] = colsum[j];
    __syncthreads();
    if (j < OUT_DIM) {
        float o = rb[j];
        for (int i = 0; i < H2D; i++) o += sv[i] * rw[i * OUT_DIM + j];
        out[j] = o;
    }
}

// -------- launch -------------------------------------------------------------
extern "C" void kernel_launch(void* const* d_in, const int* in_sizes, int n_in,
                              void* d_out, int out_size, void* d_ws, size_t ws_size,
                              hipStream_t stream) {
    const int*   x_atoms    = (const int*)d_in[0];
    const int*   edge_index = (const int*)d_in[1];
    const float* edge_attr  = (const float*)d_in[2];
    const float* embedding  = (const float*)d_in[3];
    const float* mlp_w1     = (const float*)d_in[4];
    const float* mlp_b1     = (const float*)d_in[5];
    const float* mlp_w2     = (const float*)d_in[6];
    const float* mlp_b2     = (const float*)d_in[7];
    const float* conv1_w    = (const float*)d_in[8];
    const float* conv2_w    = (const float*)d_in[9];
    const float* conv2_b    = (const float*)d_in[10];
    const float* int_lin_w  = (const float*)d_in[11];
    const float* int_lin_b  = (const float*)d_in[12];
    const float* lin1_w     = (const float*)d_in[13];
    const float* lin1_b     = (const float*)d_in[14];
    const float* lin2_w     = (const float*)d_in[15];
    const float* lin2_b     = (const float*)d_in[16];
    const float* readout_w  = (const float*)d_in[17];
    const float* readout_b  = (const float*)d_in[18];

    char* ws = (char*)d_ws;
    bf16*  hb      = (bf16*)(ws + 0);              // 12,800,000
    bf16*  xfA     = (bf16*)(ws + 12800000);       // 12,800,000
    bf16*  xfB     = (bf16*)(ws + 25600000);       // 12,800,000
    bf16*  aggb    = (bf16*)(ws + 38400000);       // 12,800,000
    float* partial = (float*)(ws + 51200000);      // 200,192
    size_t wb = 51400192;
    bf16* c1t = (bf16*)(ws + wb);                  // 196,608
    bf16* c2t = (bf16*)(ws + wb + 196608);
    bf16* ilt = (bf16*)(ws + wb + 393216);
    bf16* w1t = (bf16*)(ws + wb + 589824);         // 98,304
    bf16* w2t = (bf16*)(ws + wb + 688128);         // 196,608
    bf16* l1t = (bf16*)(ws + wb + 884736);         // 16,384
    bf16* l2t = (bf16*)(ws + wb + 901120);         // 8,192 -> ends 52,309,504
    int*   d_hist = (int*)(ws + 52309504);         // 200,000
    int*   d_rs   = (int*)(ws + 52509504);         // 200,000
    int*   d_bcur = (int*)(ws + 52709504);         // 1,024 (bucket_cur)
    int*   d_bsum = (int*)(ws + 52710528);         // 1,024
    int*   d_es   = (int*)(ws + 52711552);         // 3,200,000 -> 55,911,552
    bf16*  tab    = (bf16*)(ws + 55911552);        // 6*4097*128*2 = 6,292,992 -> 62,204,544
    int2*  d_tmp8 = (int2*)(ws + 62204544);        // 6,400,000 -> 68,604,544
    float* colsum = (float*)(ws + 68604544);       // 256 -> 68,604,800

    PrepArgs pa = { conv1_w, conv2_w, int_lin_w, mlp_w1, mlp_w2, lin1_w, lin2_w,
                    c1t, c2t, ilt, w1t, w2t, l1t, l2t, d_hist };
    prep_kernel<<<32, 256, 0, stream>>>(pa);
    table_kernel<<<LL * 65, 256, 0, stream>>>(w1t, w2t, mlp_b1, mlp_b2, tab);

    // sort edges by dst (once; graph static across layers)
    hist_kernel<<<(EE + 255) / 256, 256, 0, stream>>>(edge_index, d_hist);
    scanA_kernel<<<SB, 256, 0, stream>>>(d_hist, d_bsum);
    scanB_kernel<<<1, 256, 0, stream>>>(d_bsum);
    scanC_kernel<<<SB, 256, 0, stream>>>(d_hist, d_bsum, d_rs, d_bcur);
    scat1_kernel<<<NBUK, 256, 0, stream>>>(edge_attr, edge_index, d_bcur, d_tmp8);
    scat2_kernel<<<NBUK, 256, 0, stream>>>(d_rs, d_tmp8, d_es);

    xf0_kernel<<<NBLK, 256, 0, stream>>>(x_atoms, embedding, c1t, hb, xfA);
    bf16* xf_in = xfA;
    bf16* xf_out = xfB;
    for (int l = 0; l < LL; l++) {
        // MEASUREMENT (this round only): edge_kernel is pure & idempotent
        // (fully overwrites aggb from read-only inputs) -> 3x launch per layer.
        // dur_us = t_other + 18*t_edge; baseline 571 = t_other + 6*t_edge_old.
        // Remove the rep loop next round to close the system.
        for (int rep = 0; rep < 3; ++rep)
            edge_kernel<<<NN / 4, 256, 0, stream>>>(d_es, d_rs, d_hist, xf_in,
                                                    tab + (size_t)l * (NK + 1) * FF, aggb);
        const bf16* c1n = (l + 1 < LL) ? (c1t + (size_t)(l + 1) * FF * HH) : nullptr;
        update_kernel<<<NBLK, 256, 0, stream>>>(aggb, c2t + (size_t)l * HH * FF,
                                                conv2_b + l * HH,
                                                ilt + (size_t)l * HH * HH, int_lin_b + l * HH,
                                                hb, c1n, xf_out,
                                                l1t, lin1_b, l2t, lin2_b, partial);
        bf16* tmp = xf_in; xf_in = xf_out; xf_out = tmp;
    }
    finalA_kernel<<<64, 256, 0, stream>>>(partial, colsum);
    finalB_kernel<<<1, 64, 0, stream>>>(colsum, readout_w, readout_b, (float*)d_out);
}

// Round 2
// 699.853 us; speedup vs baseline: 1.3099x; 1.3099x over previous
//
#include <hip/hip_runtime.h>
#include <hip/hip_bf16.h>
#include <math.h>

#define NN 50000
#define EE 800000
#define HH 128
#define FF 128
#define GG 50
#define LL 6
#define H2D 64
#define OUT_DIM 12
#define NK 4096          // nearest-neighbor table intervals; knots 0..NK (4097)
#define NBLK 782         // ceil(NN/64)
#define SB 196           // scan blocks: ceil(NN/256)
#define NBUK 196         // scatter buckets: 256 nodes each

typedef __bf16 bf16;
typedef __attribute__((ext_vector_type(8))) __bf16 bf16x8;
typedef __attribute__((ext_vector_type(4))) __bf16 bf16x4;
typedef __attribute__((ext_vector_type(4))) float f32x4;
typedef __attribute__((ext_vector_type(4))) unsigned u32x4;

#define DEV __device__ __forceinline__

// fast shifted-softplus: hw v_exp/v_log, err ~1e-6 << bf16 rounding
DEV float sspf(float x) {
    return fmaxf(x, 0.f) + __logf(1.f + __expf(-fabsf(x))) - 0.69314718055994531f;
}

DEV f32x4 mfma16(bf16x8 a, bf16x8 b, f32x4 c) {
    return __builtin_amdgcn_mfma_f32_16x16x32_bf16(a, b, c, 0, 0, 0);
}

DEV float blo(unsigned u) { return __uint_as_float(u << 16); }
DEV float bhi(unsigned u) { return __uint_as_float(u & 0xffff0000u); }

// -------- prep: transpose all weights to [n][k] bf16 (+ zero hist) -----------
struct PrepArgs {
    const float *conv1_w, *conv2_w, *int_lin_w, *mlp_w1, *mlp_w2, *lin1_w, *lin2_w;
    bf16 *c1t, *c2t, *ilt, *w1t, *w2t, *l1t, *l2t;
    int* hist;
};

__global__ void prep_kernel(PrepArgs p) {
    int j = blockIdx.x;
    // fused hist zeroing (grid-stride over all 32 blocks)
    for (int i = blockIdx.x * 256 + threadIdx.x; i < NN; i += 32 * 256) p.hist[i] = 0;
    const float* src = nullptr; bf16* dst = nullptr; int R = 0, C = 0, K = 0;
    if (j < 30) {
        int l = j / 5, m = j % 5;
        switch (m) {
            case 0: src = p.conv1_w + l * HH * FF;   dst = p.c1t + l * FF * HH;  R = HH; C = FF; K = HH; break;
            case 1: src = p.conv2_w + l * FF * HH;   dst = p.c2t + l * HH * FF;  R = FF; C = HH; K = FF; break;
            case 2: src = p.int_lin_w + l * HH * HH; dst = p.ilt + l * HH * HH;  R = HH; C = HH; K = HH; break;
            case 3: src = p.mlp_w1 + l * GG * FF;    dst = p.w1t + l * FF * 64;  R = GG; C = FF; K = 64; break;
            case 4: src = p.mlp_w2 + l * FF * FF;    dst = p.w2t + l * FF * FF;  R = FF; C = FF; K = FF; break;
        }
    } else if (j == 30) { src = p.lin1_w; dst = p.l1t; R = HH;  C = H2D; K = HH; }
    else                { src = p.lin2_w; dst = p.l2t; R = H2D; C = H2D; K = H2D; }
    int total = C * K;
    for (int idx = threadIdx.x; idx < total; idx += blockDim.x) {
        int c = idx / K, r = idx - c * K;
        dst[idx] = (r < R) ? (bf16)src[r * C + c] : (bf16)0.f;
    }
}

// -------- table build via MFMA: T[l][r][:] = (ssp(g(d)@W1+b1)@W2+b2)*C(d) ----
__global__ __launch_bounds__(256) void table_kernel(const bf16* __restrict__ w1t,
                                                    const bf16* __restrict__ w2t,
                                                    const float* __restrict__ mlp_b1,
                                                    const float* __restrict__ mlp_b2,
                                                    bf16* __restrict__ tab) {
    __shared__ bf16 sW1[128 * 72];
    __shared__ bf16 sW2[128 * 136];
    __shared__ bf16 sT1[64 * 136];
    int tid = threadIdx.x;
    int l = blockIdx.x / 65, rb = blockIdx.x % 65;
    const bf16* W1 = w1t + (size_t)l * 128 * 64;
    const bf16* W2 = w2t + (size_t)l * 128 * 128;
    for (int idx = tid * 8; idx < 128 * 64; idx += 2048) {
        int n = idx >> 6, k = idx & 63;
        *(bf16x8*)&sW1[n * 72 + k] = *(const bf16x8*)(W1 + idx);
    }
    for (int idx = tid * 8; idx < 128 * 128; idx += 2048) {
        int n = idx >> 7, k = idx & 127;
        *(bf16x8*)&sW2[n * 136 + k] = *(const bf16x8*)(W2 + idx);
    }
    int w = tid >> 6, lane = tid & 63, ln = lane & 15, kg = lane >> 4;
    int rowt = rb * 64 + w * 16;
    float d1 = (float)min(rowt + ln, NK) * (10.f / NK);
    const float step = 10.f / 49.f;
    const float coeff = -0.5f / (step * step);
    __syncthreads();
    // GEMM1: in-register gaussian basis @ W1
    f32x4 acc[8] = {};
#pragma unroll
    for (int k0 = 0; k0 < 64; k0 += 32) {
        bf16x8 a;
#pragma unroll
        for (int jj = 0; jj < 8; jj++) {
            int g = k0 + kg * 8 + jj;
            float diff = d1 - g * step;
            float v = (g < GG) ? __expf(coeff * diff * diff) : 0.f;
            a[jj] = (bf16)v;
        }
#pragma unroll
        for (int t = 0; t < 8; t++) {
            bf16x8 b = *(const bf16x8*)&sW1[(t * 16 + ln) * 72 + k0 + kg * 8];
            acc[t] = mfma16(a, b, acc[t]);
        }
    }
    const float* b1 = mlp_b1 + l * FF;
#pragma unroll
    for (int t = 0; t < 8; t++) {
        int colt = t * 16 + ln;
        float bb = b1[colt];
#pragma unroll
        for (int r = 0; r < 4; r++)
            sT1[(w * 16 + kg * 4 + r) * 136 + colt] = (bf16)sspf(acc[t][r] + bb);
    }
    __syncthreads();
    f32x4 acc2[8] = {};
#pragma unroll
    for (int k0 = 0; k0 < 128; k0 += 32) {
        bf16x8 a = *(const bf16x8*)&sT1[(w * 16 + ln) * 136 + k0 + kg * 8];
#pragma unroll
        for (int t = 0; t < 8; t++) {
            bf16x8 b = *(const bf16x8*)&sW2[(t * 16 + ln) * 136 + k0 + kg * 8];
            acc2[t] = mfma16(a, b, acc2[t]);
        }
    }
    const float* b2 = mlp_b2 + l * FF;
    float Cw[4]; int rrow[4];
#pragma unroll
    for (int r = 0; r < 4; r++) {
        int rr = rowt + kg * 4 + r;
        rrow[r] = rr;
        float dd = (float)min(rr, NK) * (10.f / NK);
        Cw[r] = 0.5f * (cosf(dd * 0.31415926535897932f) + 1.f);
    }
#pragma unroll
    for (int t = 0; t < 8; t++) {
        int colt = t * 16 + ln;
        float bb = b2[colt];
#pragma unroll
        for (int r = 0; r < 4; r++) {
            if (rrow[r] <= NK)
                tab[((size_t)l * (NK + 1) + rrow[r]) * FF + colt] = (bf16)((acc2[t][r] + bb) * Cw[r]);
        }
    }
}

// -------- edge sort by dst: histogram / hierarchical scan --------------------
__global__ void hist_kernel(const int* __restrict__ eidx, int* __restrict__ hist) {
    int e = blockIdx.x * 256 + threadIdx.x;
    if (e < EE) atomicAdd(&hist[eidx[EE + e]], 1);
}

__global__ __launch_bounds__(256) void scanA_kernel(const int* __restrict__ hist,
                                                    int* __restrict__ bsum) {
    __shared__ int red[256];
    int t = threadIdx.x;
    int i = blockIdx.x * 256 + t;
    int v = (i < NN) ? hist[i] : 0;
    red[t] = v;
    __syncthreads();
    for (int off = 128; off > 0; off >>= 1) {
        if (t < off) red[t] += red[t + off];
        __syncthreads();
    }
    if (t == 0) bsum[blockIdx.x] = red[0];
}

__global__ __launch_bounds__(256) void scanB_kernel(int* __restrict__ bsum) {
    __shared__ int buf[256];
    int t = threadIdx.x;
    int v = (t < SB) ? bsum[t] : 0;
    buf[t] = v;
    __syncthreads();
    for (int off = 1; off < 256; off <<= 1) {
        int y = (t >= off) ? buf[t - off] : 0;
        __syncthreads();
        buf[t] += y;
        __syncthreads();
    }
    if (t < SB) bsum[t] = buf[t] - v;   // exclusive
}

__global__ __launch_bounds__(256) void scanC_kernel(const int* __restrict__ hist,
                                                    const int* __restrict__ bsum,
                                                    int* __restrict__ rs,
                                                    int* __restrict__ bucket_cur) {
    __shared__ int buf[256];
    int t = threadIdx.x;
    int i = blockIdx.x * 256 + t;
    int v = (i < NN) ? hist[i] : 0;
    buf[t] = v;
    __syncthreads();
    for (int off = 1; off < 256; off <<= 1) {
        int y = (t >= off) ? buf[t - off] : 0;
        __syncthreads();
        buf[t] += y;
        __syncthreads();
    }
    if (i < NN) {
        int ex = buf[t] - v + bsum[blockIdx.x];
        rs[i] = ex;
        if ((i & 255) == 0) bucket_cur[i >> 8] = ex;   // bucket base (fused bukinit)
    }
}

// -------- bucketed two-pass scatter (kills 64B-line write amplification) -----
// pass 1: 196 blocks x 4096 edges -> bucket-grouped tmp (int2: packed, dst)
__global__ __launch_bounds__(256) void scat1_kernel(const float* __restrict__ eattr,
                                                    const int* __restrict__ eidx,
                                                    int* __restrict__ bucket_cur,
                                                    int2* __restrict__ tmp8) {
    __shared__ int cnt[NBUK];
    __shared__ int res[NBUK];
    int t = threadIdx.x;
    for (int i = t; i < NBUK; i += 256) cnt[i] = 0;
    __syncthreads();
    int e0 = blockIdx.x * 4096;
    int pv[16], dd[16], bk[16];
#pragma unroll
    for (int i = 0; i < 16; i++) {
        int e = e0 + i * 256 + t;
        if (e < EE) {
            int d = eidx[EE + e];
            int k = (int)(eattr[e] * ((float)NK / 10.f) + 0.5f);
            k = min(k, NK);
            pv[i] = k | (eidx[e] << 13);
            dd[i] = d;
            bk[i] = d >> 8;
            atomicAdd(&cnt[bk[i]], 1);
        } else bk[i] = -1;
    }
    __syncthreads();
    for (int i = t; i < NBUK; i += 256) {
        int c = cnt[i];
        res[i] = (c > 0) ? atomicAdd(&bucket_cur[i], c) : 0;
        cnt[i] = 0;          // reuse as local rank counter
    }
    __syncthreads();
#pragma unroll
    for (int i = 0; i < 16; i++) {
        if (bk[i] >= 0) {
            int rank = atomicAdd(&cnt[bk[i]], 1);
            int2 v; v.x = pv[i]; v.y = dd[i];
            tmp8[res[bk[i]] + rank] = v;
        }
    }
}

// pass 2: one block per bucket -> final dst-sorted es (dense 16KB window)
__global__ __launch_bounds__(256) void scat2_kernel(const int* __restrict__ rs,
                                                    const int2* __restrict__ tmp8,
                                                    int* __restrict__ es) {
    __shared__ int off[256];
    __shared__ int loc[256];
    int b = blockIdx.x, t = threadIdx.x;
    int nb0 = b * 256;
    int nnb = min(256, NN - nb0);          // nodes in this bucket
    int base = rs[nb0];
    int end = (nb0 + 256 < NN) ? rs[nb0 + 256] : EE;
    loc[t] = 0;
    if (t < nnb) off[t] = rs[nb0 + t] - base;
    __syncthreads();
    for (int e = base + t; e < end; e += 256) {
        int2 v = tmp8[e];
        int nl = v.y - nb0;
        int rank = atomicAdd(&loc[nl], 1);
        es[base + off[nl] + rank] = v.x;
    }
}

// -------- xf0: hb = embedding[x_atoms]; xf = hb @ conv1_w (fused, layer 0) ---
__global__ __launch_bounds__(256) void xf0_kernel(const int* __restrict__ x_atoms,
                                                  const float* __restrict__ emb,
                                                  const bf16* __restrict__ c1t,
                                                  bf16* __restrict__ hb,
                                                  bf16* __restrict__ xf) {
    __shared__ bf16 sB[128 * 136];
    int tid = threadIdx.x;
    for (int idx = tid * 8; idx < 128 * 128; idx += 2048) {
        int n = idx >> 7, k = idx & 127;
        *(bf16x8*)&sB[n * 136 + k] = *(const bf16x8*)(c1t + idx);
    }
    int w = tid >> 6, lane = tid & 63, ln = lane & 15, kg = lane >> 4;
    int rowt = blockIdx.x * 64 + w * 16;
    int nrow = rowt + ln;
    int arow = min(nrow, NN - 1);
    bool rowok = nrow < NN;
    int atom = x_atoms[arow];
    __syncthreads();
    f32x4 acc[8] = {};
#pragma unroll
    for (int k0 = 0; k0 < 128; k0 += 32) {
        const float* ep = emb + (size_t)atom * HH + k0 + kg * 8;
        f32x4 u0 = *(const f32x4*)ep;
        f32x4 u1 = *(const f32x4*)(ep + 4);
        bf16x8 a;
#pragma unroll
        for (int q = 0; q < 4; q++) { a[q] = (bf16)u0[q]; a[q + 4] = (bf16)u1[q]; }
        if (rowok) *(bf16x8*)(hb + (size_t)nrow * HH + k0 + kg * 8) = a;
#pragma unroll
        for (int t = 0; t < 8; t++) {
            bf16x8 b = *(const bf16x8*)&sB[(t * 16 + ln) * 136 + k0 + kg * 8];
            acc[t] = mfma16(a, b, acc[t]);
        }
    }
#pragma unroll
    for (int t = 0; t < 8; t++) {
        int colt = t * 16 + ln;
#pragma unroll
        for (int r = 0; r < 4; r++) {
            int orow = rowt + kg * 4 + r;
            if (orow < NN) xf[orow * FF + colt] = (bf16)acc[t][r];
        }
    }
}

// -------- fused layer kernel: edge gather+agg (into LDS) -> update GEMMs -----
// Wave w aggregates nodes [rowt, rowt+16) into sT rows [w*16, w*16+16), node-major
// [node][ch] — exactly the orientation GEMM1's bfrag consumed from aggb before.
// Numerics identical to split version (same bf16 round-trip, via LDS not global).
__global__ __launch_bounds__(256) void layer_kernel(const int* __restrict__ es,
                                                    const int* __restrict__ rs,
                                                    const int* __restrict__ hist,
                                                    const bf16* __restrict__ xf,
                                                    const bf16* __restrict__ tab,
                                                    const bf16* __restrict__ c2t,
                                                    const float* __restrict__ c2b,
                                                    const bf16* __restrict__ ilt,
                                                    const float* __restrict__ ilb,
                                                    bf16* __restrict__ hb,
                                                    const bf16* __restrict__ c1n,
                                                    bf16* __restrict__ xf_out,
                                                    const bf16* __restrict__ l1t,
                                                    const float* __restrict__ l1b,
                                                    const bf16* __restrict__ l2t,
                                                    const float* __restrict__ l2b,
                                                    float* __restrict__ partial) {
    __shared__ bf16 sB[128 * 136];   // restaged per GEMM
    __shared__ bf16 sT[64 * 136];    // edge agg -> ssp(v) -> h_new (in-place per wave)
    int tid = threadIdx.x;
    int w = tid >> 6, lane = tid & 63, ln = lane & 15, kg = lane >> 4;
    int rowt = blockIdx.x * 64 + w * 16;
    int nrow = rowt + ln;                 // this thread's node (transposed layout)
    int arow = min(nrow, NN - 1);
    bool rowok = nrow < NN;
    // prefetch residual h: node nrow, feats t*16+kg*4 .. +4
    bf16x4 hpre[8];
#pragma unroll
    for (int t = 0; t < 8; t++)
        hpre[t] = *(const bf16x4*)(hb + (size_t)arow * HH + t * 16 + kg * 4);
    // stage sB = c2t (overlaps gather; consumed after the sync below)
    for (int idx = tid * 8; idx < 128 * 128; idx += 2048) {
        int n = idx >> 7, k = idx & 127;
        *(bf16x8*)&sB[n * 136 + k] = *(const bf16x8*)(c2t + idx);
    }
    // ---- edge phase: wave-local CSR gather, node nd+1's edge list prefetched ----
    int myrs = 0, mydeg = 0;
    {
        int nid = rowt + lane;            // lanes 0..15 carry the wave's 16 nodes
        if (lane < 16 && nid < NN) { myrs = rs[nid]; mydeg = hist[nid]; }
    }
    int s0 = __shfl(myrs, 0), d0 = __shfl(mydeg, 0);
    int pvn = (lane < min(d0, 64)) ? es[s0 + lane] : 0;
    for (int nd = 0; nd < 16; nd++) {
        int start = __shfl(myrs, nd);
        int deg   = __shfl(mydeg, nd);
        int pv = pvn;
        if (nd + 1 < 16) {
            int s1 = __shfl(myrs, nd + 1);
            int d1 = __shfl(mydeg, nd + 1);
            pvn = (lane < min(d1, 64)) ? es[s1 + lane] : 0;
        }
        float a0 = 0.f, a1 = 0.f, a2 = 0.f, a3 = 0.f;
        float a4 = 0.f, a5 = 0.f, a6 = 0.f, a7 = 0.f;
        for (int base = 0; base < deg; base += 64) {
            int cnt = min(deg - base, 64);
            if (base > 0) pv = (lane < cnt) ? es[start + base + lane] : 0;
            int iters = (cnt + 7) >> 3;   // 8 edges per wave-iter (2 per quarter)
#pragma unroll 2
            for (int j = 0; j < iters; j++) {
                int j0 = 8 * j + kg;      // quarter's first edge
                int j1 = j0 + 4;          // quarter's second edge
                bool va = j0 < cnt, vb = j1 < cnt;
                int v0 = __shfl(pv, j0);
                int v1 = __shfl(pv, j1);
                int ka = v0 & 8191, sa = v0 >> 13;
                int kb = v1 & 8191, sb1 = v1 >> 13;
                u32x4 tpa = *(const u32x4*)(tab + (size_t)ka * FF + 8 * ln);
                u32x4 xua = *(const u32x4*)(xf + (size_t)sa * FF + 8 * ln);
                u32x4 tpb = *(const u32x4*)(tab + (size_t)kb * FF + 8 * ln);
                u32x4 xub = *(const u32x4*)(xf + (size_t)sb1 * FF + 8 * ln);
                unsigned ta0 = va ? tpa.x : 0u;
                unsigned ta1 = va ? tpa.y : 0u;
                unsigned ta2 = va ? tpa.z : 0u;
                unsigned ta3 = va ? tpa.w : 0u;
                unsigned tb0 = vb ? tpb.x : 0u;
                unsigned tb1 = vb ? tpb.y : 0u;
                unsigned tb2 = vb ? tpb.z : 0u;
                unsigned tb3 = vb ? tpb.w : 0u;
                a0 = fmaf(blo(ta0), blo(xua.x), a0);
                a1 = fmaf(bhi(ta0), bhi(xua.x), a1);
                a2 = fmaf(blo(ta1), blo(xua.y), a2);
                a3 = fmaf(bhi(ta1), bhi(xua.y), a3);
                a4 = fmaf(blo(ta2), blo(xua.z), a4);
                a5 = fmaf(bhi(ta2), bhi(xua.z), a5);
                a6 = fmaf(blo(ta3), blo(xua.w), a6);
                a7 = fmaf(bhi(ta3), bhi(xua.w), a7);
                a0 = fmaf(blo(tb0), blo(xub.x), a0);
                a1 = fmaf(bhi(tb0), bhi(xub.x), a1);
                a2 = fmaf(blo(tb1), blo(xub.y), a2);
                a3 = fmaf(bhi(tb1), bhi(xub.y), a3);
                a4 = fmaf(blo(tb2), blo(xub.z), a4);
                a5 = fmaf(bhi(tb2), bhi(xub.z), a5);
                a6 = fmaf(blo(tb3), blo(xub.w), a6);
                a7 = fmaf(bhi(tb3), bhi(xub.w), a7);
            }
        }
        a0 += __shfl_xor(a0, 16); a0 += __shfl_xor(a0, 32);
        a1 += __shfl_xor(a1, 16); a1 += __shfl_xor(a1, 32);
        a2 += __shfl_xor(a2, 16); a2 += __shfl_xor(a2, 32);
        a3 += __shfl_xor(a3, 16); a3 += __shfl_xor(a3, 32);
        a4 += __shfl_xor(a4, 16); a4 += __shfl_xor(a4, 32);
        a5 += __shfl_xor(a5, 16); a5 += __shfl_xor(a5, 32);
        a6 += __shfl_xor(a6, 16); a6 += __shfl_xor(a6, 32);
        a7 += __shfl_xor(a7, 16); a7 += __shfl_xor(a7, 32);
        if (kg == 0) {
            bf16x8 pk;
            pk[0] = (bf16)a0; pk[1] = (bf16)a1; pk[2] = (bf16)a2; pk[3] = (bf16)a3;
            pk[4] = (bf16)a4; pk[5] = (bf16)a5; pk[6] = (bf16)a6; pk[7] = (bf16)a7;
            *(bf16x8*)&sT[(w * 16 + nd) * 136 + 8 * ln] = pk;
        }
    }
    __syncthreads();   // sB (c2t) staged + all agg rows in sT
    // GEMM1 (Ct): out[feat][node] = conv2^T @ agg^T  (operand-swapped MFMA)
    f32x4 acc[8] = {};
#pragma unroll
    for (int k0 = 0; k0 < 128; k0 += 32) {
        bf16x8 bfrag = *(const bf16x8*)&sT[(w * 16 + ln) * 136 + k0 + kg * 8];
#pragma unroll
        for (int t = 0; t < 8; t++) {
            bf16x8 afrag = *(const bf16x8*)&sB[(t * 16 + ln) * 136 + k0 + kg * 8];
            acc[t] = mfma16(afrag, bfrag, acc[t]);
        }
    }
    // epilogue1: in-place sT row update is safe — wave-lockstep, wave-private rows
#pragma unroll
    for (int t = 0; t < 8; t++) {
        f32x4 bb = *(const f32x4*)(c2b + t * 16 + kg * 4);
        bf16x4 pk;
#pragma unroll
        for (int r = 0; r < 4; r++) pk[r] = (bf16)sspf(acc[t][r] + bb[r]);
        *(bf16x4*)&sT[(w * 16 + ln) * 136 + t * 16 + kg * 4] = pk;
    }
    __syncthreads();
    for (int idx = tid * 8; idx < 128 * 128; idx += 2048) {
        int n = idx >> 7, k = idx & 127;
        *(bf16x8*)&sB[n * 136 + k] = *(const bf16x8*)(ilt + idx);
    }
    __syncthreads();
    f32x4 acc2[8] = {};
#pragma unroll
    for (int k0 = 0; k0 < 128; k0 += 32) {
        bf16x8 bfrag = *(const bf16x8*)&sT[(w * 16 + ln) * 136 + k0 + kg * 8];
#pragma unroll
        for (int t = 0; t < 8; t++) {
            bf16x8 afrag = *(const bf16x8*)&sB[(t * 16 + ln) * 136 + k0 + kg * 8];
            acc2[t] = mfma16(afrag, bfrag, acc2[t]);
        }
    }
    bool is_last = (c1n == nullptr);
    // epilogue2: residual add, vector stores (own sT rows only -> no barrier needed)
#pragma unroll
    for (int t = 0; t < 8; t++) {
        f32x4 bb = *(const f32x4*)(ilb + t * 16 + kg * 4);
        bf16x4 pk;
#pragma unroll
        for (int r = 0; r < 4; r++)
            pk[r] = (bf16)((float)hpre[t][r] + acc2[t][r] + bb[r]);
        if (rowok && !is_last) *(bf16x4*)(hb + (size_t)nrow * HH + t * 16 + kg * 4) = pk;
        *(bf16x4*)&sT[(w * 16 + ln) * 136 + t * 16 + kg * 4] = pk;
    }
    if (!is_last) {
        // fused next-layer xf = h_new @ conv1_next (same transposed form)
        __syncthreads();
        for (int idx = tid * 8; idx < 128 * 128; idx += 2048) {
            int n = idx >> 7, k = idx & 127;
            *(bf16x8*)&sB[n * 136 + k] = *(const bf16x8*)(c1n + idx);
        }
        __syncthreads();
        f32x4 acc3[8] = {};
#pragma unroll
        for (int k0 = 0; k0 < 128; k0 += 32) {
            bf16x8 bfrag = *(const bf16x8*)&sT[(w * 16 + ln) * 136 + k0 + kg * 8];
#pragma unroll
            for (int t = 0; t < 8; t++) {
                bf16x8 afrag = *(const bf16x8*)&sB[(t * 16 + ln) * 136 + k0 + kg * 8];
                acc3[t] = mfma16(afrag, bfrag, acc3[t]);
            }
        }
#pragma unroll
        for (int t = 0; t < 8; t++) {
            bf16x4 pk;
#pragma unroll
            for (int r = 0; r < 4; r++) pk[r] = (bf16)acc3[t][r];
            if (rowok) *(bf16x4*)(xf_out + (size_t)nrow * FF + t * 16 + kg * 4) = pk;
        }
    } else {
        // fused head: ssp(h@lin1+b)@lin2+b, per-block partial sum (runs once)
        __syncthreads();
        for (int idx = tid * 8; idx < 64 * 128; idx += 2048) {
            int n = idx >> 7, k = idx & 127;
            *(bf16x8*)&sB[n * 136 + k] = *(const bf16x8*)(l1t + idx);
        }
        __syncthreads();
        f32x4 acch[4] = {};
#pragma unroll
        for (int k0 = 0; k0 < 128; k0 += 32) {
            bf16x8 a = *(const bf16x8*)&sT[(w * 16 + ln) * 136 + k0 + kg * 8];
#pragma unroll
            for (int t = 0; t < 4; t++) {
                bf16x8 b = *(const bf16x8*)&sB[(t * 16 + ln) * 136 + k0 + kg * 8];
                acch[t] = mfma16(a, b, acch[t]);
            }
        }
#pragma unroll
        for (int t = 0; t < 4; t++) {
            int colt = t * 16 + ln;
            float bb = l1b[colt];
#pragma unroll
            for (int r = 0; r < 4; r++)
                sT[(w * 16 + kg * 4 + r) * 136 + colt] = (bf16)sspf(acch[t][r] + bb);
        }
        __syncthreads();
        for (int idx = tid * 8; idx < 64 * 64; idx += 2048) {
            int n = idx >> 6, k = idx & 63;
            *(bf16x8*)&sB[n * 136 + k] = *(const bf16x8*)(l2t + idx);
        }
        __syncthreads();
        f32x4 acc2h[4] = {};
#pragma unroll
        for (int k0 = 0; k0 < 64; k0 += 32) {
            bf16x8 a = *(const bf16x8*)&sT[(w * 16 + ln) * 136 + k0 + kg * 8];
#pragma unroll
            for (int t = 0; t < 4; t++) {
                bf16x8 b = *(const bf16x8*)&sB[(t * 16 + ln) * 136 + k0 + kg * 8];
                acc2h[t] = mfma16(a, b, acc2h[t]);
            }
        }
        __syncthreads();   // all sT reads done; reuse as f32 scratch
        float* sPart = (float*)sT;
#pragma unroll
        for (int t = 0; t < 4; t++) {
            int colt = t * 16 + ln;
            float bb = l2b[colt];
            float v = 0.f;
#pragma unroll
            for (int r = 0; r < 4; r++) {
                int orow = rowt + kg * 4 + r;
                if (orow < NN) v += acc2h[t][r] + bb;
            }
            v += __shfl_xor(v, 16);
            v += __shfl_xor(v, 32);
            if (kg == 0) sPart[w * 64 + colt] = v;
        }
        __syncthreads();
        if (tid < 64) {
            float s = sPart[tid] + sPart[64 + tid] + sPart[128 + tid] + sPart[192 + tid];
            partial[blockIdx.x * 64 + tid] = s;
        }
    }
}

// -------- finalA: one block per column, parallel reduce over 782 partials ----
__global__ __launch_bounds__(256) void finalA_kernel(const float* __restrict__ partial,
                                                     float* __restrict__ colsum) {
    __shared__ float red[256];
    int c = blockIdx.x, t = threadIdx.x;
    float s = 0.f;
    for (int b = t; b < NBLK; b += 256) s += partial[b * 64 + c];
    red[t] = s;
    __syncthreads();
    for (int off = 128; off > 0; off >>= 1) {
        if (t < off) red[t] += red[t + off];
        __syncthreads();
    }
    if (t == 0) colsum[c] = red[0];
}

// -------- finalB: readout GEMV (64x12, trivial) ------------------------------
__global__ __launch_bounds__(64) void finalB_kernel(const float* __restrict__ colsum,
                                                    const float* __restrict__ rw,
                                                    const float* __restrict__ rb,
                                                    float* __restrict__ out) {
    __shared__ float sv[64];
    int j = threadIdx.x;
    sv[j] = colsum[j];
    __syncthreads();
    if (j < OUT_DIM) {
        float o = rb[j];
        for (int i = 0; i < H2D; i++) o += sv[i] * rw[i * OUT_DIM + j];
        out[j] = o;
    }
}

// -------- launch -------------------------------------------------------------
extern "C" void kernel_launch(void* const* d_in, const int* in_sizes, int n_in,
                              void* d_out, int out_size, void* d_ws, size_t ws_size,
                              hipStream_t stream) {
    const int*   x_atoms    = (const int*)d_in[0];
    const int*   edge_index = (const int*)d_in[1];
    const float* edge_attr  = (const float*)d_in[2];
    const float* embedding  = (const float*)d_in[3];
    const float* mlp_w1     = (const float*)d_in[4];
    const float* mlp_b1     = (const float*)d_in[5];
    const float* mlp_w2     = (const float*)d_in[6];
    const float* mlp_b2     = (const float*)d_in[7];
    const float* conv1_w    = (const float*)d_in[8];
    const float* conv2_w    = (const float*)d_in[9];
    const float* conv2_b    = (const float*)d_in[10];
    const float* int_lin_w  = (const float*)d_in[11];
    const float* int_lin_b  = (const float*)d_in[12];
    const float* lin1_w     = (const float*)d_in[13];
    const float* lin1_b     = (const float*)d_in[14];
    const float* lin2_w     = (const float*)d_in[15];
    const float* lin2_b     = (const float*)d_in[16];
    const float* readout_w  = (const float*)d_in[17];
    const float* readout_b  = (const float*)d_in[18];

    char* ws = (char*)d_ws;
    bf16*  hb      = (bf16*)(ws + 0);              // 12,800,000
    bf16*  xfA     = (bf16*)(ws + 12800000);       // 12,800,000
    bf16*  xfB     = (bf16*)(ws + 25600000);       // 12,800,000
    float* partial = (float*)(ws + 51200000);      // 200,192 (aggb slot now unused)
    size_t wb = 51400192;
    bf16* c1t = (bf16*)(ws + wb);                  // 196,608
    bf16* c2t = (bf16*)(ws + wb + 196608);
    bf16* ilt = (bf16*)(ws + wb + 393216);
    bf16* w1t = (bf16*)(ws + wb + 589824);         // 98,304
    bf16* w2t = (bf16*)(ws + wb + 688128);         // 196,608
    bf16* l1t = (bf16*)(ws + wb + 884736);         // 16,384
    bf16* l2t = (bf16*)(ws + wb + 901120);         // 8,192 -> ends 52,309,504
    int*   d_hist = (int*)(ws + 52309504);         // 200,000
    int*   d_rs   = (int*)(ws + 52509504);         // 200,000
    int*   d_bcur = (int*)(ws + 52709504);         // 1,024 (bucket_cur)
    int*   d_bsum = (int*)(ws + 52710528);         // 1,024
    int*   d_es   = (int*)(ws + 52711552);         // 3,200,000 -> 55,911,552
    bf16*  tab    = (bf16*)(ws + 55911552);        // 6*4097*128*2 = 6,292,992 -> 62,204,544
    int2*  d_tmp8 = (int2*)(ws + 62204544);        // 6,400,000 -> 68,604,544
    float* colsum = (float*)(ws + 68604544);       // 256 -> 68,604,800

    PrepArgs pa = { conv1_w, conv2_w, int_lin_w, mlp_w1, mlp_w2, lin1_w, lin2_w,
                    c1t, c2t, ilt, w1t, w2t, l1t, l2t, d_hist };
    prep_kernel<<<32, 256, 0, stream>>>(pa);
    table_kernel<<<LL * 65, 256, 0, stream>>>(w1t, w2t, mlp_b1, mlp_b2, tab);

    // sort edges by dst (once; graph static across layers)
    hist_kernel<<<(EE + 255) / 256, 256, 0, stream>>>(edge_index, d_hist);
    scanA_kernel<<<SB, 256, 0, stream>>>(d_hist, d_bsum);
    scanB_kernel<<<1, 256, 0, stream>>>(d_bsum);
    scanC_kernel<<<SB, 256, 0, stream>>>(d_hist, d_bsum, d_rs, d_bcur);
    scat1_kernel<<<NBUK, 256, 0, stream>>>(edge_attr, edge_index, d_bcur, d_tmp8);
    scat2_kernel<<<NBUK, 256, 0, stream>>>(d_rs, d_tmp8, d_es);

    xf0_kernel<<<NBLK, 256, 0, stream>>>(x_atoms, embedding, c1t, hb, xfA);
    bf16* xf_in = xfA;
    bf16* xf_out = xfB;
    for (int l = 0; l < LL; l++) {
        const bf16* c1n = (l + 1 < LL) ? (c1t + (size_t)(l + 1) * FF * HH) : nullptr;
        layer_kernel<<<NBLK, 256, 0, stream>>>(d_es, d_rs, d_hist, xf_in,
                                               tab + (size_t)l * (NK + 1) * FF,
                                               c2t + (size_t)l * HH * FF, conv2_b + l * HH,
                                               ilt + (size_t)l * HH * HH, int_lin_b + l * HH,
                                               hb, c1n, xf_out,
                                               l1t, lin1_b, l2t, lin2_b, partial);
        bf16* tmp = xf_in; xf_in = xf_out; xf_out = tmp;
    }
    finalA_kernel<<<64, 256, 0, stream>>>(partial, colsum);
    finalB_kernel<<<1, 64, 0, stream>>>(colsum, readout_w, readout_b, (float*)d_out);
}

// Round 3
// 542.612 us; speedup vs baseline: 1.6895x; 1.2898x over previous
//
#include <hip/hip_runtime.h>
#include <hip/hip_bf16.h>
#include <math.h>

#define NN 50000
#define EE 800000
#define HH 128
#define FF 128
#define GG 50
#define LL 6
#define H2D 64
#define OUT_DIM 12
#define NK 4096          // nearest-neighbor table intervals; knots 0..NK (4097)
#define NBLK 782         // ceil(NN/64)
#define SB 196           // scan blocks: ceil(NN/256)
#define NBUK 196         // scatter buckets: 256 nodes each

typedef __bf16 bf16;
typedef __attribute__((ext_vector_type(8))) __bf16 bf16x8;
typedef __attribute__((ext_vector_type(4))) __bf16 bf16x4;
typedef __attribute__((ext_vector_type(4))) float f32x4;
typedef __attribute__((ext_vector_type(4))) unsigned u32x4;

#define DEV __device__ __forceinline__

// fast shifted-softplus: hw v_exp/v_log, err ~1e-6 << bf16 rounding
DEV float sspf(float x) {
    return fmaxf(x, 0.f) + __logf(1.f + __expf(-fabsf(x))) - 0.69314718055994531f;
}

DEV f32x4 mfma16(bf16x8 a, bf16x8 b, f32x4 c) {
    return __builtin_amdgcn_mfma_f32_16x16x32_bf16(a, b, c, 0, 0, 0);
}

DEV float blo(unsigned u) { return __uint_as_float(u << 16); }
DEV float bhi(unsigned u) { return __uint_as_float(u & 0xffff0000u); }

// -------- prep: transpose all weights to [n][k] bf16 (+ zero hist) -----------
struct PrepArgs {
    const float *conv1_w, *conv2_w, *int_lin_w, *mlp_w1, *mlp_w2, *lin1_w, *lin2_w;
    bf16 *c1t, *c2t, *ilt, *w1t, *w2t, *l1t, *l2t;
    int* hist;
};

__global__ void prep_kernel(PrepArgs p) {
    int j = blockIdx.x;
    // fused hist zeroing (grid-stride over all 32 blocks)
    for (int i = blockIdx.x * 256 + threadIdx.x; i < NN; i += 32 * 256) p.hist[i] = 0;
    const float* src = nullptr; bf16* dst = nullptr; int R = 0, C = 0, K = 0;
    if (j < 30) {
        int l = j / 5, m = j % 5;
        switch (m) {
            case 0: src = p.conv1_w + l * HH * FF;   dst = p.c1t + l * FF * HH;  R = HH; C = FF; K = HH; break;
            case 1: src = p.conv2_w + l * FF * HH;   dst = p.c2t + l * HH * FF;  R = FF; C = HH; K = FF; break;
            case 2: src = p.int_lin_w + l * HH * HH; dst = p.ilt + l * HH * HH;  R = HH; C = HH; K = HH; break;
            case 3: src = p.mlp_w1 + l * GG * FF;    dst = p.w1t + l * FF * 64;  R = GG; C = FF; K = 64; break;
            case 4: src = p.mlp_w2 + l * FF * FF;    dst = p.w2t + l * FF * FF;  R = FF; C = FF; K = FF; break;
        }
    } else if (j == 30) { src = p.lin1_w; dst = p.l1t; R = HH;  C = H2D; K = HH; }
    else                { src = p.lin2_w; dst = p.l2t; R = H2D; C = H2D; K = H2D; }
    int total = C * K;
    for (int idx = threadIdx.x; idx < total; idx += blockDim.x) {
        int c = idx / K, r = idx - c * K;
        dst[idx] = (r < R) ? (bf16)src[r * C + c] : (bf16)0.f;
    }
}

// -------- table build via MFMA: T[l][r][:] = (ssp(g(d)@W1+b1)@W2+b2)*C(d) ----
__global__ __launch_bounds__(256) void table_kernel(const bf16* __restrict__ w1t,
                                                    const bf16* __restrict__ w2t,
                                                    const float* __restrict__ mlp_b1,
                                                    const float* __restrict__ mlp_b2,
                                                    bf16* __restrict__ tab) {
    __shared__ bf16 sW1[128 * 72];
    __shared__ bf16 sW2[128 * 136];
    __shared__ bf16 sT1[64 * 136];
    int tid = threadIdx.x;
    int l = blockIdx.x / 65, rb = blockIdx.x % 65;
    const bf16* W1 = w1t + (size_t)l * 128 * 64;
    const bf16* W2 = w2t + (size_t)l * 128 * 128;
    for (int idx = tid * 8; idx < 128 * 64; idx += 2048) {
        int n = idx >> 6, k = idx & 63;
        *(bf16x8*)&sW1[n * 72 + k] = *(const bf16x8*)(W1 + idx);
    }
    for (int idx = tid * 8; idx < 128 * 128; idx += 2048) {
        int n = idx >> 7, k = idx & 127;
        *(bf16x8*)&sW2[n * 136 + k] = *(const bf16x8*)(W2 + idx);
    }
    int w = tid >> 6, lane = tid & 63, ln = lane & 15, kg = lane >> 4;
    int rowt = rb * 64 + w * 16;
    float d1 = (float)min(rowt + ln, NK) * (10.f / NK);
    const float step = 10.f / 49.f;
    const float coeff = -0.5f / (step * step);
    __syncthreads();
    // GEMM1: in-register gaussian basis @ W1
    f32x4 acc[8] = {};
#pragma unroll
    for (int k0 = 0; k0 < 64; k0 += 32) {
        bf16x8 a;
#pragma unroll
        for (int jj = 0; jj < 8; jj++) {
            int g = k0 + kg * 8 + jj;
            float diff = d1 - g * step;
            float v = (g < GG) ? __expf(coeff * diff * diff) : 0.f;
            a[jj] = (bf16)v;
        }
#pragma unroll
        for (int t = 0; t < 8; t++) {
            bf16x8 b = *(const bf16x8*)&sW1[(t * 16 + ln) * 72 + k0 + kg * 8];
            acc[t] = mfma16(a, b, acc[t]);
        }
    }
    const float* b1 = mlp_b1 + l * FF;
#pragma unroll
    for (int t = 0; t < 8; t++) {
        int colt = t * 16 + ln;
        float bb = b1[colt];
#pragma unroll
        for (int r = 0; r < 4; r++)
            sT1[(w * 16 + kg * 4 + r) * 136 + colt] = (bf16)sspf(acc[t][r] + bb);
    }
    __syncthreads();
    f32x4 acc2[8] = {};
#pragma unroll
    for (int k0 = 0; k0 < 128; k0 += 32) {
        bf16x8 a = *(const bf16x8*)&sT1[(w * 16 + ln) * 136 + k0 + kg * 8];
#pragma unroll
        for (int t = 0; t < 8; t++) {
            bf16x8 b = *(const bf16x8*)&sW2[(t * 16 + ln) * 136 + k0 + kg * 8];
            acc2[t] = mfma16(a, b, acc2[t]);
        }
    }
    const float* b2 = mlp_b2 + l * FF;
    float Cw[4]; int rrow[4];
#pragma unroll
    for (int r = 0; r < 4; r++) {
        int rr = rowt + kg * 4 + r;
        rrow[r] = rr;
        float dd = (float)min(rr, NK) * (10.f / NK);
        Cw[r] = 0.5f * (cosf(dd * 0.31415926535897932f) + 1.f);
    }
#pragma unroll
    for (int t = 0; t < 8; t++) {
        int colt = t * 16 + ln;
        float bb = b2[colt];
#pragma unroll
        for (int r = 0; r < 4; r++) {
            if (rrow[r] <= NK)
                tab[((size_t)l * (NK + 1) + rrow[r]) * FF + colt] = (bf16)((acc2[t][r] + bb) * Cw[r]);
        }
    }
}

// -------- edge sort by dst: histogram / hierarchical scan --------------------
__global__ void hist_kernel(const int* __restrict__ eidx, int* __restrict__ hist) {
    int e = blockIdx.x * 256 + threadIdx.x;
    if (e < EE) atomicAdd(&hist[eidx[EE + e]], 1);
}

__global__ __launch_bounds__(256) void scanA_kernel(const int* __restrict__ hist,
                                                    int* __restrict__ bsum) {
    __shared__ int red[256];
    int t = threadIdx.x;
    int i = blockIdx.x * 256 + t;
    int v = (i < NN) ? hist[i] : 0;
    red[t] = v;
    __syncthreads();
    for (int off = 128; off > 0; off >>= 1) {
        if (t < off) red[t] += red[t + off];
        __syncthreads();
    }
    if (t == 0) bsum[blockIdx.x] = red[0];
}

__global__ __launch_bounds__(256) void scanB_kernel(int* __restrict__ bsum) {
    __shared__ int buf[256];
    int t = threadIdx.x;
    int v = (t < SB) ? bsum[t] : 0;
    buf[t] = v;
    __syncthreads();
    for (int off = 1; off < 256; off <<= 1) {
        int y = (t >= off) ? buf[t - off] : 0;
        __syncthreads();
        buf[t] += y;
        __syncthreads();
    }
    if (t < SB) bsum[t] = buf[t] - v;   // exclusive
}

__global__ __launch_bounds__(256) void scanC_kernel(const int* __restrict__ hist,
                                                    const int* __restrict__ bsum,
                                                    int* __restrict__ rs,
                                                    int* __restrict__ bucket_cur) {
    __shared__ int buf[256];
    int t = threadIdx.x;
    int i = blockIdx.x * 256 + t;
    int v = (i < NN) ? hist[i] : 0;
    buf[t] = v;
    __syncthreads();
    for (int off = 1; off < 256; off <<= 1) {
        int y = (t >= off) ? buf[t - off] : 0;
        __syncthreads();
        buf[t] += y;
        __syncthreads();
    }
    if (i < NN) {
        int ex = buf[t] - v + bsum[blockIdx.x];
        rs[i] = ex;
        if ((i & 255) == 0) bucket_cur[i >> 8] = ex;   // bucket base (fused bukinit)
    }
}

// -------- bucketed two-pass scatter (kills 64B-line write amplification) -----
// pass 1: 196 blocks x 4096 edges -> bucket-grouped tmp (int2: packed, dst)
__global__ __launch_bounds__(256) void scat1_kernel(const float* __restrict__ eattr,
                                                    const int* __restrict__ eidx,
                                                    int* __restrict__ bucket_cur,
                                                    int2* __restrict__ tmp8) {
    __shared__ int cnt[NBUK];
    __shared__ int res[NBUK];
    int t = threadIdx.x;
    for (int i = t; i < NBUK; i += 256) cnt[i] = 0;
    __syncthreads();
    int e0 = blockIdx.x * 4096;
    int pv[16], dd[16], bk[16];
#pragma unroll
    for (int i = 0; i < 16; i++) {
        int e = e0 + i * 256 + t;
        if (e < EE) {
            int d = eidx[EE + e];
            int k = (int)(eattr[e] * ((float)NK / 10.f) + 0.5f);
            k = min(k, NK);
            pv[i] = k | (eidx[e] << 13);
            dd[i] = d;
            bk[i] = d >> 8;
            atomicAdd(&cnt[bk[i]], 1);
        } else bk[i] = -1;
    }
    __syncthreads();
    for (int i = t; i < NBUK; i += 256) {
        int c = cnt[i];
        res[i] = (c > 0) ? atomicAdd(&bucket_cur[i], c) : 0;
        cnt[i] = 0;          // reuse as local rank counter
    }
    __syncthreads();
#pragma unroll
    for (int i = 0; i < 16; i++) {
        if (bk[i] >= 0) {
            int rank = atomicAdd(&cnt[bk[i]], 1);
            int2 v; v.x = pv[i]; v.y = dd[i];
            tmp8[res[bk[i]] + rank] = v;
        }
    }
}

// pass 2: one block per bucket -> final dst-sorted es (dense 16KB window)
__global__ __launch_bounds__(256) void scat2_kernel(const int* __restrict__ rs,
                                                    const int2* __restrict__ tmp8,
                                                    int* __restrict__ es) {
    __shared__ int off[256];
    __shared__ int loc[256];
    int b = blockIdx.x, t = threadIdx.x;
    int nb0 = b * 256;
    int nnb = min(256, NN - nb0);          // nodes in this bucket
    int base = rs[nb0];
    int end = (nb0 + 256 < NN) ? rs[nb0 + 256] : EE;
    loc[t] = 0;
    if (t < nnb) off[t] = rs[nb0 + t] - base;
    __syncthreads();
    for (int e = base + t; e < end; e += 256) {
        int2 v = tmp8[e];
        int nl = v.y - nb0;
        int rank = atomicAdd(&loc[nl], 1);
        es[base + off[nl] + rank] = v.x;
    }
}

// -------- xf0: hb = embedding[x_atoms]; xf = hb @ conv1_w (fused, layer 0) ---
__global__ __launch_bounds__(256) void xf0_kernel(const int* __restrict__ x_atoms,
                                                  const float* __restrict__ emb,
                                                  const bf16* __restrict__ c1t,
                                                  bf16* __restrict__ hb,
                                                  bf16* __restrict__ xf) {
    __shared__ bf16 sB[128 * 136];
    int tid = threadIdx.x;
    for (int idx = tid * 8; idx < 128 * 128; idx += 2048) {
        int n = idx >> 7, k = idx & 127;
        *(bf16x8*)&sB[n * 136 + k] = *(const bf16x8*)(c1t + idx);
    }
    int w = tid >> 6, lane = tid & 63, ln = lane & 15, kg = lane >> 4;
    int rowt = blockIdx.x * 64 + w * 16;
    int nrow = rowt + ln;
    int arow = min(nrow, NN - 1);
    bool rowok = nrow < NN;
    int atom = x_atoms[arow];
    __syncthreads();
    f32x4 acc[8] = {};
#pragma unroll
    for (int k0 = 0; k0 < 128; k0 += 32) {
        const float* ep = emb + (size_t)atom * HH + k0 + kg * 8;
        f32x4 u0 = *(const f32x4*)ep;
        f32x4 u1 = *(const f32x4*)(ep + 4);
        bf16x8 a;
#pragma unroll
        for (int q = 0; q < 4; q++) { a[q] = (bf16)u0[q]; a[q + 4] = (bf16)u1[q]; }
        if (rowok) *(bf16x8*)(hb + (size_t)nrow * HH + k0 + kg * 8) = a;
#pragma unroll
        for (int t = 0; t < 8; t++) {
            bf16x8 b = *(const bf16x8*)&sB[(t * 16 + ln) * 136 + k0 + kg * 8];
            acc[t] = mfma16(a, b, acc[t]);
        }
    }
#pragma unroll
    for (int t = 0; t < 8; t++) {
        int colt = t * 16 + ln;
#pragma unroll
        for (int r = 0; r < 4; r++) {
            int orow = rowt + kg * 4 + r;
            if (orow < NN) xf[orow * FF + colt] = (bf16)acc[t][r];
        }
    }
}

// -------- edge kernel: CSR, one wave/node, nearest-knot, 8 edges/wave-iter ---
__global__ __launch_bounds__(256) void edge_kernel(const int* __restrict__ es,
                                                   const int* __restrict__ rs,
                                                   const int* __restrict__ hist,
                                                   const bf16* __restrict__ xf,
                                                   const bf16* __restrict__ tab,
                                                   bf16* __restrict__ aggb) {
    int tid = threadIdx.x;
    int w = tid >> 6, lane = tid & 63;
    int q = lane >> 4, cl = lane & 15;      // quarter q; lane covers ch [8cl,8cl+8)
    int n = blockIdx.x * 4 + w;
    int start = rs[n], deg = hist[n];
    float a0 = 0.f, a1 = 0.f, a2 = 0.f, a3 = 0.f;
    float a4 = 0.f, a5 = 0.f, a6 = 0.f, a7 = 0.f;
    for (int base = 0; base < deg; base += 64) {
        int cnt = min(deg - base, 64);
        int pv = (lane < cnt) ? es[start + base + lane] : 0;
        int iters = (cnt + 7) >> 3;         // 8 edges per wave-iter
#pragma unroll 2
        for (int j = 0; j < iters; j++) {
            int j0 = 8 * j + q;             // quarter's first edge
            int j1 = j0 + 4;                // quarter's second edge
            bool va = j0 < cnt, vb = j1 < cnt;
            int v0 = __shfl(pv, j0);
            int v1 = __shfl(pv, j1);
            int ka = v0 & 8191, sa = v0 >> 13;
            int kb = v1 & 8191, sb1 = v1 >> 13;
            u32x4 tpa = *(const u32x4*)(tab + (size_t)ka * FF + 8 * cl);
            u32x4 xua = *(const u32x4*)(xf + (size_t)sa * FF + 8 * cl);
            u32x4 tpb = *(const u32x4*)(tab + (size_t)kb * FF + 8 * cl);
            u32x4 xub = *(const u32x4*)(xf + (size_t)sb1 * FF + 8 * cl);
            unsigned ta0 = va ? tpa.x : 0u;
            unsigned ta1 = va ? tpa.y : 0u;
            unsigned ta2 = va ? tpa.z : 0u;
            unsigned ta3 = va ? tpa.w : 0u;
            unsigned tb0 = vb ? tpb.x : 0u;
            unsigned tb1 = vb ? tpb.y : 0u;
            unsigned tb2 = vb ? tpb.z : 0u;
            unsigned tb3 = vb ? tpb.w : 0u;
            a0 = fmaf(blo(ta0), blo(xua.x), a0);
            a1 = fmaf(bhi(ta0), bhi(xua.x), a1);
            a2 = fmaf(blo(ta1), blo(xua.y), a2);
            a3 = fmaf(bhi(ta1), bhi(xua.y), a3);
            a4 = fmaf(blo(ta2), blo(xua.z), a4);
            a5 = fmaf(bhi(ta2), bhi(xua.z), a5);
            a6 = fmaf(blo(ta3), blo(xua.w), a6);
            a7 = fmaf(bhi(ta3), bhi(xua.w), a7);
            a0 = fmaf(blo(tb0), blo(xub.x), a0);
            a1 = fmaf(bhi(tb0), bhi(xub.x), a1);
            a2 = fmaf(blo(tb1), blo(xub.y), a2);
            a3 = fmaf(bhi(tb1), bhi(xub.y), a3);
            a4 = fmaf(blo(tb2), blo(xub.z), a4);
            a5 = fmaf(bhi(tb2), bhi(xub.z), a5);
            a6 = fmaf(blo(tb3), blo(xub.w), a6);
            a7 = fmaf(bhi(tb3), bhi(xub.w), a7);
        }
    }
    a0 += __shfl_xor(a0, 16); a0 += __shfl_xor(a0, 32);
    a1 += __shfl_xor(a1, 16); a1 += __shfl_xor(a1, 32);
    a2 += __shfl_xor(a2, 16); a2 += __shfl_xor(a2, 32);
    a3 += __shfl_xor(a3, 16); a3 += __shfl_xor(a3, 32);
    a4 += __shfl_xor(a4, 16); a4 += __shfl_xor(a4, 32);
    a5 += __shfl_xor(a5, 16); a5 += __shfl_xor(a5, 32);
    a6 += __shfl_xor(a6, 16); a6 += __shfl_xor(a6, 32);
    a7 += __shfl_xor(a7, 16); a7 += __shfl_xor(a7, 32);
    if (q == 0) {
        bf16x8 pk;
        pk[0] = (bf16)a0; pk[1] = (bf16)a1; pk[2] = (bf16)a2; pk[3] = (bf16)a3;
        pk[4] = (bf16)a4; pk[5] = (bf16)a5; pk[6] = (bf16)a6; pk[7] = (bf16)a7;
        *(bf16x8*)(aggb + (size_t)n * FF + 8 * cl) = pk;
    }
}

// -------- update: half-sB double-pass GEMMs (LDS 34.8KB -> 4 blocks/CU) ------
// sB holds 64 weight-out-rows at a time; each GEMM runs two passes (t 0..3 per
// pass). Same staging bytes as full-sB, +33% occupancy for latency hiding.
__global__ __launch_bounds__(256) void update_kernel(const bf16* __restrict__ aggb,
                                                     const bf16* __restrict__ c2t,
                                                     const float* __restrict__ c2b,
                                                     const bf16* __restrict__ ilt,
                                                     const float* __restrict__ ilb,
                                                     bf16* __restrict__ hb,
                                                     const bf16* __restrict__ c1n,
                                                     bf16* __restrict__ xf_out,
                                                     const bf16* __restrict__ l1t,
                                                     const float* __restrict__ l1b,
                                                     const bf16* __restrict__ l2t,
                                                     const float* __restrict__ l2b,
                                                     float* __restrict__ partial) {
    __shared__ bf16 sB[64 * 136];    // half-weight tile (restaged per pass)
    __shared__ bf16 sT[64 * 136];    // per-wave intermediate (own 16 rows each)
    int tid = threadIdx.x;
    int w = tid >> 6, lane = tid & 63, ln = lane & 15, kg = lane >> 4;
    int rowt = blockIdx.x * 64 + w * 16;
    int nrow = rowt + ln;                 // this thread's node (transposed layout)
    int arow = min(nrow, NN - 1);
    bool rowok = nrow < NN;
    // global prefetches: residual h + agg row (hide LLC latency under staging)
    bf16x4 hpre[8];
#pragma unroll
    for (int t = 0; t < 8; t++)
        hpre[t] = *(const bf16x4*)(hb + (size_t)arow * HH + t * 16 + kg * 4);
    bf16x8 breg[4];
#pragma unroll
    for (int k0 = 0; k0 < 4; k0++)
        breg[k0] = *(const bf16x8*)(aggb + (size_t)arow * FF + k0 * 32 + kg * 8);

    // GEMM1 (Ct): out[feat][node] = conv2^T @ agg^T  (operand-swapped MFMA)
    f32x4 acc[8] = {};
#pragma unroll
    for (int h = 0; h < 2; h++) {
        __syncthreads();   // prior sB readers done (cheap at h=0)
        for (int idx = tid * 8; idx < 64 * 128; idx += 2048)
            *(bf16x8*)&sB[(idx >> 7) * 136 + (idx & 127)] =
                *(const bf16x8*)(c2t + h * 64 * 128 + idx);
        __syncthreads();
#pragma unroll
        for (int k0 = 0; k0 < 128; k0 += 32) {
#pragma unroll
            for (int t = 0; t < 4; t++) {
                bf16x8 afrag = *(const bf16x8*)&sB[(t * 16 + ln) * 136 + k0 + kg * 8];
                acc[h * 4 + t] = mfma16(afrag, breg[k0 >> 5], acc[h * 4 + t]);
            }
        }
    }
    // epilogue1: thread holds feats t*16+kg*4+[0..4) of node nrow (own sT rows)
#pragma unroll
    for (int t = 0; t < 8; t++) {
        f32x4 bb = *(const f32x4*)(c2b + t * 16 + kg * 4);
        bf16x4 pk;
#pragma unroll
        for (int r = 0; r < 4; r++) pk[r] = (bf16)sspf(acc[t][r] + bb[r]);
        *(bf16x4*)&sT[(w * 16 + ln) * 136 + t * 16 + kg * 4] = pk;
    }
    // GEMM2: int_lin
    f32x4 acc2[8] = {};
#pragma unroll
    for (int h = 0; h < 2; h++) {
        __syncthreads();
        for (int idx = tid * 8; idx < 64 * 128; idx += 2048)
            *(bf16x8*)&sB[(idx >> 7) * 136 + (idx & 127)] =
                *(const bf16x8*)(ilt + h * 64 * 128 + idx);
        __syncthreads();
#pragma unroll
        for (int k0 = 0; k0 < 128; k0 += 32) {
            bf16x8 bfrag = *(const bf16x8*)&sT[(w * 16 + ln) * 136 + k0 + kg * 8];
#pragma unroll
            for (int t = 0; t < 4; t++) {
                bf16x8 afrag = *(const bf16x8*)&sB[(t * 16 + ln) * 136 + k0 + kg * 8];
                acc2[h * 4 + t] = mfma16(afrag, bfrag, acc2[h * 4 + t]);
            }
        }
    }
    bool is_last = (c1n == nullptr);
    // epilogue2: residual add; own-wave sT rows (in-wave program order is safe)
#pragma unroll
    for (int t = 0; t < 8; t++) {
        f32x4 bb = *(const f32x4*)(ilb + t * 16 + kg * 4);
        bf16x4 pk;
#pragma unroll
        for (int r = 0; r < 4; r++)
            pk[r] = (bf16)((float)hpre[t][r] + acc2[t][r] + bb[r]);
        if (rowok && !is_last) *(bf16x4*)(hb + (size_t)nrow * HH + t * 16 + kg * 4) = pk;
        *(bf16x4*)&sT[(w * 16 + ln) * 136 + t * 16 + kg * 4] = pk;
    }
    if (!is_last) {
        // fused next-layer xf = h_new @ conv1_next (same transposed form)
        f32x4 acc3[8] = {};
#pragma unroll
        for (int h = 0; h < 2; h++) {
            __syncthreads();
            for (int idx = tid * 8; idx < 64 * 128; idx += 2048)
                *(bf16x8*)&sB[(idx >> 7) * 136 + (idx & 127)] =
                    *(const bf16x8*)(c1n + h * 64 * 128 + idx);
            __syncthreads();
#pragma unroll
            for (int k0 = 0; k0 < 128; k0 += 32) {
                bf16x8 bfrag = *(const bf16x8*)&sT[(w * 16 + ln) * 136 + k0 + kg * 8];
#pragma unroll
                for (int t = 0; t < 4; t++) {
                    bf16x8 afrag = *(const bf16x8*)&sB[(t * 16 + ln) * 136 + k0 + kg * 8];
                    acc3[h * 4 + t] = mfma16(afrag, bfrag, acc3[h * 4 + t]);
                }
            }
        }
#pragma unroll
        for (int t = 0; t < 8; t++) {
            bf16x4 pk;
#pragma unroll
            for (int r = 0; r < 4; r++) pk[r] = (bf16)acc3[t][r];
            if (rowok) *(bf16x4*)(xf_out + (size_t)nrow * FF + t * 16 + kg * 4) = pk;
        }
    } else {
        // fused head: ssp(h@lin1+b)@lin2+b, per-block partial sum (runs once)
        // l1t is 64 out-rows x 128 k -> fits half-sB in one pass
        __syncthreads();
        for (int idx = tid * 8; idx < 64 * 128; idx += 2048)
            *(bf16x8*)&sB[(idx >> 7) * 136 + (idx & 127)] = *(const bf16x8*)(l1t + idx);
        __syncthreads();
        f32x4 acch[4] = {};
#pragma unroll
        for (int k0 = 0; k0 < 128; k0 += 32) {
            bf16x8 a = *(const bf16x8*)&sT[(w * 16 + ln) * 136 + k0 + kg * 8];
#pragma unroll
            for (int t = 0; t < 4; t++) {
                bf16x8 b = *(const bf16x8*)&sB[(t * 16 + ln) * 136 + k0 + kg * 8];
                acch[t] = mfma16(a, b, acch[t]);
            }
        }
#pragma unroll
        for (int t = 0; t < 4; t++) {
            int colt = t * 16 + ln;
            float bb = l1b[colt];
#pragma unroll
            for (int r = 0; r < 4; r++)
                sT[(w * 16 + kg * 4 + r) * 136 + colt] = (bf16)sspf(acch[t][r] + bb);
        }
        __syncthreads();
        for (int idx = tid * 8; idx < 64 * 64; idx += 2048) {
            int n = idx >> 6, k = idx & 63;
            *(bf16x8*)&sB[n * 136 + k] = *(const bf16x8*)(l2t + idx);
        }
        __syncthreads();
        f32x4 acc2h[4] = {};
#pragma unroll
        for (int k0 = 0; k0 < 64; k0 += 32) {
            bf16x8 a = *(const bf16x8*)&sT[(w * 16 + ln) * 136 + k0 + kg * 8];
#pragma unroll
            for (int t = 0; t < 4; t++) {
                bf16x8 b = *(const bf16x8*)&sB[(t * 16 + ln) * 136 + k0 + kg * 8];
                acc2h[t] = mfma16(a, b, acc2h[t]);
            }
        }
        __syncthreads();   // all sT reads done; reuse as f32 scratch
        float* sPart = (float*)sT;
#pragma unroll
        for (int t = 0; t < 4; t++) {
            int colt = t * 16 + ln;
            float bb = l2b[colt];
            float v = 0.f;
#pragma unroll
            for (int r = 0; r < 4; r++) {
                int orow = rowt + kg * 4 + r;
                if (orow < NN) v += acc2h[t][r] + bb;
            }
            v += __shfl_xor(v, 16);
            v += __shfl_xor(v, 32);
            if (kg == 0) sPart[w * 64 + colt] = v;
        }
        __syncthreads();
        if (tid < 64) {
            float s = sPart[tid] + sPart[64 + tid] + sPart[128 + tid] + sPart[192 + tid];
            partial[blockIdx.x * 64 + tid] = s;
        }
    }
}

// -------- finalA: one block per column, parallel reduce over 782 partials ----
__global__ __launch_bounds__(256) void finalA_kernel(const float* __restrict__ partial,
                                                     float* __restrict__ colsum) {
    __shared__ float red[256];
    int c = blockIdx.x, t = threadIdx.x;
    float s = 0.f;
    for (int b = t; b < NBLK; b += 256) s += partial[b * 64 + c];
    red[t] = s;
    __syncthreads();
    for (int off = 128; off > 0; off >>= 1) {
        if (t < off) red[t] += red[t + off];
        __syncthreads();
    }
    if (t == 0) colsum[c] = red[0];
}

// -------- finalB: readout GEMV (64x12, trivial) ------------------------------
__global__ __launch_bounds__(64) void finalB_kernel(const float* __restrict__ colsum,
                                                    const float* __restrict__ rw,
                                                    const float* __restrict__ rb,
                                                    float* __restrict__ out) {
    __shared__ float sv[64];
    int j = threadIdx.x;
    sv[j] = colsum[j];
    __syncthreads();
    if (j < OUT_DIM) {
        float o = rb[j];
        for (int i = 0; i < H2D; i++) o += sv[i] * rw[i * OUT_DIM + j];
        out[j] = o;
    }
}

// -------- launch -------------------------------------------------------------
extern "C" void kernel_launch(void* const* d_in, const int* in_sizes, int n_in,
                              void* d_out, int out_size, void* d_ws, size_t ws_size,
                              hipStream_t stream) {
    const int*   x_atoms    = (const int*)d_in[0];
    const int*   edge_index = (const int*)d_in[1];
    const float* edge_attr  = (const float*)d_in[2];
    const float* embedding  = (const float*)d_in[3];
    const float* mlp_w1     = (const float*)d_in[4];
    const float* mlp_b1     = (const float*)d_in[5];
    const float* mlp_w2     = (const float*)d_in[6];
    const float* mlp_b2     = (const float*)d_in[7];
    const float* conv1_w    = (const float*)d_in[8];
    const float* conv2_w    = (const float*)d_in[9];
    const float* conv2_b    = (const float*)d_in[10];
    const float* int_lin_w  = (const float*)d_in[11];
    const float* int_lin_b  = (const float*)d_in[12];
    const float* lin1_w     = (const float*)d_in[13];
    const float* lin1_b     = (const float*)d_in[14];
    const float* lin2_w     = (const float*)d_in[15];
    const float* lin2_b     = (const float*)d_in[16];
    const float* readout_w  = (const float*)d_in[17];
    const float* readout_b  = (const float*)d_in[18];

    char* ws = (char*)d_ws;
    bf16*  hb      = (bf16*)(ws + 0);              // 12,800,000
    bf16*  xfA     = (bf16*)(ws + 12800000);       // 12,800,000
    bf16*  xfB     = (bf16*)(ws + 25600000);       // 12,800,000
    bf16*  aggb    = (bf16*)(ws + 38400000);       // 12,800,000
    float* partial = (float*)(ws + 51200000);      // 200,192
    size_t wb = 51400192;
    bf16* c1t = (bf16*)(ws + wb);                  // 196,608
    bf16* c2t = (bf16*)(ws + wb + 196608);
    bf16* ilt = (bf16*)(ws + wb + 393216);
    bf16* w1t = (bf16*)(ws + wb + 589824);         // 98,304
    bf16* w2t = (bf16*)(ws + wb + 688128);         // 196,608
    bf16* l1t = (bf16*)(ws + wb + 884736);         // 16,384
    bf16* l2t = (bf16*)(ws + wb + 901120);         // 8,192 -> ends 52,309,504
    int*   d_hist = (int*)(ws + 52309504);         // 200,000
    int*   d_rs   = (int*)(ws + 52509504);         // 200,000
    int*   d_bcur = (int*)(ws + 52709504);         // 1,024 (bucket_cur)
    int*   d_bsum = (int*)(ws + 52710528);         // 1,024
    int*   d_es   = (int*)(ws + 52711552);         // 3,200,000 -> 55,911,552
    bf16*  tab    = (bf16*)(ws + 55911552);        // 6*4097*128*2 = 6,292,992 -> 62,204,544
    int2*  d_tmp8 = (int2*)(ws + 62204544);        // 6,400,000 -> 68,604,544
    float* colsum = (float*)(ws + 68604544);       // 256 -> 68,604,800

    PrepArgs pa = { conv1_w, conv2_w, int_lin_w, mlp_w1, mlp_w2, lin1_w, lin2_w,
                    c1t, c2t, ilt, w1t, w2t, l1t, l2t, d_hist };
    prep_kernel<<<32, 256, 0, stream>>>(pa);
    table_kernel<<<LL * 65, 256, 0, stream>>>(w1t, w2t, mlp_b1, mlp_b2, tab);

    // sort edges by dst (once; graph static across layers)
    hist_kernel<<<(EE + 255) / 256, 256, 0, stream>>>(edge_index, d_hist);
    scanA_kernel<<<SB, 256, 0, stream>>>(d_hist, d_bsum);
    scanB_kernel<<<1, 256, 0, stream>>>(d_bsum);
    scanC_kernel<<<SB, 256, 0, stream>>>(d_hist, d_bsum, d_rs, d_bcur);
    scat1_kernel<<<NBUK, 256, 0, stream>>>(edge_attr, edge_index, d_bcur, d_tmp8);
    scat2_kernel<<<NBUK, 256, 0, stream>>>(d_rs, d_tmp8, d_es);

    xf0_kernel<<<NBLK, 256, 0, stream>>>(x_atoms, embedding, c1t, hb, xfA);
    bf16* xf_in = xfA;
    bf16* xf_out = xfB;
    for (int l = 0; l < LL; l++) {
        edge_kernel<<<NN / 4, 256, 0, stream>>>(d_es, d_rs, d_hist, xf_in,
                                                tab + (size_t)l * (NK + 1) * FF, aggb);
        const bf16* c1n = (l + 1 < LL) ? (c1t + (size_t)(l + 1) * FF * HH) : nullptr;
        update_kernel<<<NBLK, 256, 0, stream>>>(aggb, c2t + (size_t)l * HH * FF,
                                                conv2_b + l * HH,
                                                ilt + (size_t)l * HH * HH, int_lin_b + l * HH,
                                                hb, c1n, xf_out,
                                                l1t, lin1_b, l2t, lin2_b, partial);
        bf16* tmp = xf_in; xf_in = xf_out; xf_out = tmp;
    }
    finalA_kernel<<<64, 256, 0, stream>>>(partial, colsum);
    finalB_kernel<<<1, 64, 0, stream>>>(colsum, readout_w, readout_b, (float*)d_out);
}

// Round 4
// 539.857 us; speedup vs baseline: 1.6982x; 1.0051x over previous
//
#include <hip/hip_runtime.h>
#include <hip/hip_bf16.h>
#include <math.h>

#define NN 50000
#define EE 800000
#define HH 128
#define FF 128
#define GG 50
#define LL 6
#define H2D 64
#define OUT_DIM 12
#define NK 4096          // nearest-neighbor table intervals; knots 0..NK (4097)
#define NBLK 782         // ceil(NN/64)  (xf0 grid)
#define NB2 391          // ceil(NN/128) (update grid, 128 nodes/block)
#define SB 196           // scan blocks: ceil(NN/256)
#define NBUK 196         // scatter buckets: 256 nodes each

typedef __bf16 bf16;
typedef __attribute__((ext_vector_type(8))) __bf16 bf16x8;
typedef __attribute__((ext_vector_type(4))) __bf16 bf16x4;
typedef __attribute__((ext_vector_type(4))) float f32x4;
typedef __attribute__((ext_vector_type(4))) unsigned u32x4;

#define DEV __device__ __forceinline__

// fast shifted-softplus: hw v_exp/v_log, err ~1e-6 << bf16 rounding
DEV float sspf(float x) {
    return fmaxf(x, 0.f) + __logf(1.f + __expf(-fabsf(x))) - 0.69314718055994531f;
}

DEV f32x4 mfma16(bf16x8 a, bf16x8 b, f32x4 c) {
    return __builtin_amdgcn_mfma_f32_16x16x32_bf16(a, b, c, 0, 0, 0);
}

DEV float blo(unsigned u) { return __uint_as_float(u << 16); }
DEV float bhi(unsigned u) { return __uint_as_float(u & 0xffff0000u); }

// -------- prep: transpose all weights to [n][k] bf16 (+ zero hist) -----------
struct PrepArgs {
    const float *conv1_w, *conv2_w, *int_lin_w, *mlp_w1, *mlp_w2, *lin1_w, *lin2_w;
    bf16 *c1t, *c2t, *ilt, *w1t, *w2t, *l1t, *l2t;
    int* hist;
};

__global__ void prep_kernel(PrepArgs p) {
    int j = blockIdx.x;
    // fused hist zeroing (grid-stride over all 32 blocks)
    for (int i = blockIdx.x * 256 + threadIdx.x; i < NN; i += 32 * 256) p.hist[i] = 0;
    const float* src = nullptr; bf16* dst = nullptr; int R = 0, C = 0, K = 0;
    if (j < 30) {
        int l = j / 5, m = j % 5;
        switch (m) {
            case 0: src = p.conv1_w + l * HH * FF;   dst = p.c1t + l * FF * HH;  R = HH; C = FF; K = HH; break;
            case 1: src = p.conv2_w + l * FF * HH;   dst = p.c2t + l * HH * FF;  R = FF; C = HH; K = FF; break;
            case 2: src = p.int_lin_w + l * HH * HH; dst = p.ilt + l * HH * HH;  R = HH; C = HH; K = HH; break;
            case 3: src = p.mlp_w1 + l * GG * FF;    dst = p.w1t + l * FF * 64;  R = GG; C = FF; K = 64; break;
            case 4: src = p.mlp_w2 + l * FF * FF;    dst = p.w2t + l * FF * FF;  R = FF; C = FF; K = FF; break;
        }
    } else if (j == 30) { src = p.lin1_w; dst = p.l1t; R = HH;  C = H2D; K = HH; }
    else                { src = p.lin2_w; dst = p.l2t; R = H2D; C = H2D; K = H2D; }
    int total = C * K;
    for (int idx = threadIdx.x; idx < total; idx += blockDim.x) {
        int c = idx / K, r = idx - c * K;
        dst[idx] = (r < R) ? (bf16)src[r * C + c] : (bf16)0.f;
    }
}

// -------- table build via MFMA: T[l][r][:] = (ssp(g(d)@W1+b1)@W2+b2)*C(d) ----
__global__ __launch_bounds__(256) void table_kernel(const bf16* __restrict__ w1t,
                                                    const bf16* __restrict__ w2t,
                                                    const float* __restrict__ mlp_b1,
                                                    const float* __restrict__ mlp_b2,
                                                    bf16* __restrict__ tab) {
    __shared__ bf16 sW1[128 * 72];
    __shared__ bf16 sW2[128 * 136];
    __shared__ bf16 sT1[64 * 136];
    int tid = threadIdx.x;
    int l = blockIdx.x / 65, rb = blockIdx.x % 65;
    const bf16* W1 = w1t + (size_t)l * 128 * 64;
    const bf16* W2 = w2t + (size_t)l * 128 * 128;
    for (int idx = tid * 8; idx < 128 * 64; idx += 2048) {
        int n = idx >> 6, k = idx & 63;
        *(bf16x8*)&sW1[n * 72 + k] = *(const bf16x8*)(W1 + idx);
    }
    for (int idx = tid * 8; idx < 128 * 128; idx += 2048) {
        int n = idx >> 7, k = idx & 127;
        *(bf16x8*)&sW2[n * 136 + k] = *(const bf16x8*)(W2 + idx);
    }
    int w = tid >> 6, lane = tid & 63, ln = lane & 15, kg = lane >> 4;
    int rowt = rb * 64 + w * 16;
    float d1 = (float)min(rowt + ln, NK) * (10.f / NK);
    const float step = 10.f / 49.f;
    const float coeff = -0.5f / (step * step);
    __syncthreads();
    // GEMM1: in-register gaussian basis @ W1
    f32x4 acc[8] = {};
#pragma unroll
    for (int k0 = 0; k0 < 64; k0 += 32) {
        bf16x8 a;
#pragma unroll
        for (int jj = 0; jj < 8; jj++) {
            int g = k0 + kg * 8 + jj;
            float diff = d1 - g * step;
            float v = (g < GG) ? __expf(coeff * diff * diff) : 0.f;
            a[jj] = (bf16)v;
        }
#pragma unroll
        for (int t = 0; t < 8; t++) {
            bf16x8 b = *(const bf16x8*)&sW1[(t * 16 + ln) * 72 + k0 + kg * 8];
            acc[t] = mfma16(a, b, acc[t]);
        }
    }
    const float* b1 = mlp_b1 + l * FF;
#pragma unroll
    for (int t = 0; t < 8; t++) {
        int colt = t * 16 + ln;
        float bb = b1[colt];
#pragma unroll
        for (int r = 0; r < 4; r++)
            sT1[(w * 16 + kg * 4 + r) * 136 + colt] = (bf16)sspf(acc[t][r] + bb);
    }
    __syncthreads();
    f32x4 acc2[8] = {};
#pragma unroll
    for (int k0 = 0; k0 < 128; k0 += 32) {
        bf16x8 a = *(const bf16x8*)&sT1[(w * 16 + ln) * 136 + k0 + kg * 8];
#pragma unroll
        for (int t = 0; t < 8; t++) {
            bf16x8 b = *(const bf16x8*)&sW2[(t * 16 + ln) * 136 + k0 + kg * 8];
            acc2[t] = mfma16(a, b, acc2[t]);
        }
    }
    const float* b2 = mlp_b2 + l * FF;
    float Cw[4]; int rrow[4];
#pragma unroll
    for (int r = 0; r < 4; r++) {
        int rr = rowt + kg * 4 + r;
        rrow[r] = rr;
        float dd = (float)min(rr, NK) * (10.f / NK);
        Cw[r] = 0.5f * (cosf(dd * 0.31415926535897932f) + 1.f);
    }
#pragma unroll
    for (int t = 0; t < 8; t++) {
        int colt = t * 16 + ln;
        float bb = b2[colt];
#pragma unroll
        for (int r = 0; r < 4; r++) {
            if (rrow[r] <= NK)
                tab[((size_t)l * (NK + 1) + rrow[r]) * FF + colt] = (bf16)((acc2[t][r] + bb) * Cw[r]);
        }
    }
}

// -------- edge sort by dst: histogram / hierarchical scan --------------------
__global__ void hist_kernel(const int* __restrict__ eidx, int* __restrict__ hist) {
    int e = blockIdx.x * 256 + threadIdx.x;
    if (e < EE) atomicAdd(&hist[eidx[EE + e]], 1);
}

__global__ __launch_bounds__(256) void scanA_kernel(const int* __restrict__ hist,
                                                    int* __restrict__ bsum) {
    __shared__ int red[256];
    int t = threadIdx.x;
    int i = blockIdx.x * 256 + t;
    int v = (i < NN) ? hist[i] : 0;
    red[t] = v;
    __syncthreads();
    for (int off = 128; off > 0; off >>= 1) {
        if (t < off) red[t] += red[t + off];
        __syncthreads();
    }
    if (t == 0) bsum[blockIdx.x] = red[0];
}

// scanC now also computes its own block base from raw bsum (scanB folded in)
__global__ __launch_bounds__(256) void scanC_kernel(const int* __restrict__ hist,
                                                    const int* __restrict__ bsum,
                                                    int* __restrict__ rs,
                                                    int* __restrict__ bucket_cur) {
    __shared__ int buf[256];
    __shared__ int bbuf[256];
    int t = threadIdx.x;
    int i = blockIdx.x * 256 + t;
    int v = (i < NN) ? hist[i] : 0;
    buf[t] = v;
    bbuf[t] = (t < SB && t < blockIdx.x) ? bsum[t] : 0;
    __syncthreads();
    for (int off = 128; off > 0; off >>= 1) {
        if (t < off) bbuf[t] += bbuf[t + off];
        __syncthreads();
    }
    int base = bbuf[0];
    for (int off = 1; off < 256; off <<= 1) {
        int y = (t >= off) ? buf[t - off] : 0;
        __syncthreads();
        buf[t] += y;
        __syncthreads();
    }
    if (i < NN) {
        int ex = buf[t] - v + base;
        rs[i] = ex;
        if ((i & 255) == 0) bucket_cur[i >> 8] = ex;   // bucket base (fused bukinit)
    }
}

// -------- bucketed two-pass scatter (kills 64B-line write amplification) -----
// pass 1: 196 blocks x 4096 edges -> bucket-grouped tmp (int2: packed, dst)
__global__ __launch_bounds__(256) void scat1_kernel(const float* __restrict__ eattr,
                                                    const int* __restrict__ eidx,
                                                    int* __restrict__ bucket_cur,
                                                    int2* __restrict__ tmp8) {
    __shared__ int cnt[NBUK];
    __shared__ int res[NBUK];
    int t = threadIdx.x;
    for (int i = t; i < NBUK; i += 256) cnt[i] = 0;
    __syncthreads();
    int e0 = blockIdx.x * 4096;
    int pv[16], dd[16], bk[16];
#pragma unroll
    for (int i = 0; i < 16; i++) {
        int e = e0 + i * 256 + t;
        if (e < EE) {
            int d = eidx[EE + e];
            int k = (int)(eattr[e] * ((float)NK / 10.f) + 0.5f);
            k = min(k, NK);
            pv[i] = k | (eidx[e] << 13);
            dd[i] = d;
            bk[i] = d >> 8;
            atomicAdd(&cnt[bk[i]], 1);
        } else bk[i] = -1;
    }
    __syncthreads();
    for (int i = t; i < NBUK; i += 256) {
        int c = cnt[i];
        res[i] = (c > 0) ? atomicAdd(&bucket_cur[i], c) : 0;
        cnt[i] = 0;          // reuse as local rank counter
    }
    __syncthreads();
#pragma unroll
    for (int i = 0; i < 16; i++) {
        if (bk[i] >= 0) {
            int rank = atomicAdd(&cnt[bk[i]], 1);
            int2 v; v.x = pv[i]; v.y = dd[i];
            tmp8[res[bk[i]] + rank] = v;
        }
    }
}

// pass 2: one block per bucket -> final dst-sorted es (dense 16KB window)
__global__ __launch_bounds__(256) void scat2_kernel(const int* __restrict__ rs,
                                                    const int2* __restrict__ tmp8,
                                                    int* __restrict__ es) {
    __shared__ int off[256];
    __shared__ int loc[256];
    int b = blockIdx.x, t = threadIdx.x;
    int nb0 = b * 256;
    int nnb = min(256, NN - nb0);          // nodes in this bucket
    int base = rs[nb0];
    int end = (nb0 + 256 < NN) ? rs[nb0 + 256] : EE;
    loc[t] = 0;
    if (t < nnb) off[t] = rs[nb0 + t] - base;
    __syncthreads();
    for (int e = base + t; e < end; e += 256) {
        int2 v = tmp8[e];
        int nl = v.y - nb0;
        int rank = atomicAdd(&loc[nl], 1);
        es[base + off[nl] + rank] = v.x;
    }
}

// -------- xf0: hb = embedding[x_atoms]; xf = hb @ conv1_w (fused, layer 0) ---
__global__ __launch_bounds__(256) void xf0_kernel(const int* __restrict__ x_atoms,
                                                  const float* __restrict__ emb,
                                                  const bf16* __restrict__ c1t,
                                                  bf16* __restrict__ hb,
                                                  bf16* __restrict__ xf) {
    __shared__ bf16 sB[128 * 136];
    int tid = threadIdx.x;
    for (int idx = tid * 8; idx < 128 * 128; idx += 2048) {
        int n = idx >> 7, k = idx & 127;
        *(bf16x8*)&sB[n * 136 + k] = *(const bf16x8*)(c1t + idx);
    }
    int w = tid >> 6, lane = tid & 63, ln = lane & 15, kg = lane >> 4;
    int rowt = blockIdx.x * 64 + w * 16;
    int nrow = rowt + ln;
    int arow = min(nrow, NN - 1);
    bool rowok = nrow < NN;
    int atom = x_atoms[arow];
    __syncthreads();
    f32x4 acc[8] = {};
#pragma unroll
    for (int k0 = 0; k0 < 128; k0 += 32) {
        const float* ep = emb + (size_t)atom * HH + k0 + kg * 8;
        f32x4 u0 = *(const f32x4*)ep;
        f32x4 u1 = *(const f32x4*)(ep + 4);
        bf16x8 a;
#pragma unroll
        for (int q = 0; q < 4; q++) { a[q] = (bf16)u0[q]; a[q + 4] = (bf16)u1[q]; }
        if (rowok) *(bf16x8*)(hb + (size_t)nrow * HH + k0 + kg * 8) = a;
#pragma unroll
        for (int t = 0; t < 8; t++) {
            bf16x8 b = *(const bf16x8*)&sB[(t * 16 + ln) * 136 + k0 + kg * 8];
            acc[t] = mfma16(a, b, acc[t]);
        }
    }
#pragma unroll
    for (int t = 0; t < 8; t++) {
        int colt = t * 16 + ln;
#pragma unroll
        for (int r = 0; r < 4; r++) {
            int orow = rowt + kg * 4 + r;
            if (orow < NN) xf[orow * FF + colt] = (bf16)acc[t][r];
        }
    }
}

// -------- edge kernel: CSR, one wave/node, nearest-knot, 8 edges/wave-iter ---
__global__ __launch_bounds__(256) void edge_kernel(const int* __restrict__ es,
                                                   const int* __restrict__ rs,
                                                   const int* __restrict__ hist,
                                                   const bf16* __restrict__ xf,
                                                   const bf16* __restrict__ tab,
                                                   bf16* __restrict__ aggb) {
    int tid = threadIdx.x;
    int w = tid >> 6, lane = tid & 63;
    int q = lane >> 4, cl = lane & 15;      // quarter q; lane covers ch [8cl,8cl+8)
    int n = blockIdx.x * 4 + w;
    int start = rs[n], deg = hist[n];
    float a0 = 0.f, a1 = 0.f, a2 = 0.f, a3 = 0.f;
    float a4 = 0.f, a5 = 0.f, a6 = 0.f, a7 = 0.f;
    for (int base = 0; base < deg; base += 64) {
        int cnt = min(deg - base, 64);
        int pv = (lane < cnt) ? es[start + base + lane] : 0;
        int iters = (cnt + 7) >> 3;         // 8 edges per wave-iter
#pragma unroll 2
        for (int j = 0; j < iters; j++) {
            int j0 = 8 * j + q;             // quarter's first edge
            int j1 = j0 + 4;                // quarter's second edge
            bool va = j0 < cnt, vb = j1 < cnt;
            int v0 = __shfl(pv, j0);
            int v1 = __shfl(pv, j1);
            int ka = v0 & 8191, sa = v0 >> 13;
            int kb = v1 & 8191, sb1 = v1 >> 13;
            u32x4 tpa = *(const u32x4*)(tab + (size_t)ka * FF + 8 * cl);
            u32x4 xua = *(const u32x4*)(xf + (size_t)sa * FF + 8 * cl);
            u32x4 tpb = *(const u32x4*)(tab + (size_t)kb * FF + 8 * cl);
            u32x4 xub = *(const u32x4*)(xf + (size_t)sb1 * FF + 8 * cl);
            unsigned ta0 = va ? tpa.x : 0u;
            unsigned ta1 = va ? tpa.y : 0u;
            unsigned ta2 = va ? tpa.z : 0u;
            unsigned ta3 = va ? tpa.w : 0u;
            unsigned tb0 = vb ? tpb.x : 0u;
            unsigned tb1 = vb ? tpb.y : 0u;
            unsigned tb2 = vb ? tpb.z : 0u;
            unsigned tb3 = vb ? tpb.w : 0u;
            a0 = fmaf(blo(ta0), blo(xua.x), a0);
            a1 = fmaf(bhi(ta0), bhi(xua.x), a1);
            a2 = fmaf(blo(ta1), blo(xua.y), a2);
            a3 = fmaf(bhi(ta1), bhi(xua.y), a3);
            a4 = fmaf(blo(ta2), blo(xua.z), a4);
            a5 = fmaf(bhi(ta2), bhi(xua.z), a5);
            a6 = fmaf(blo(ta3), blo(xua.w), a6);
            a7 = fmaf(bhi(ta3), bhi(xua.w), a7);
            a0 = fmaf(blo(tb0), blo(xub.x), a0);
            a1 = fmaf(bhi(tb0), bhi(xub.x), a1);
            a2 = fmaf(blo(tb1), blo(xub.y), a2);
            a3 = fmaf(bhi(tb1), bhi(xub.y), a3);
            a4 = fmaf(blo(tb2), blo(xub.z), a4);
            a5 = fmaf(bhi(tb2), bhi(xub.z), a5);
            a6 = fmaf(blo(tb3), blo(xub.w), a6);
            a7 = fmaf(bhi(tb3), bhi(xub.w), a7);
        }
    }
    a0 += __shfl_xor(a0, 16); a0 += __shfl_xor(a0, 32);
    a1 += __shfl_xor(a1, 16); a1 += __shfl_xor(a1, 32);
    a2 += __shfl_xor(a2, 16); a2 += __shfl_xor(a2, 32);
    a3 += __shfl_xor(a3, 16); a3 += __shfl_xor(a3, 32);
    a4 += __shfl_xor(a4, 16); a4 += __shfl_xor(a4, 32);
    a5 += __shfl_xor(a5, 16); a5 += __shfl_xor(a5, 32);
    a6 += __shfl_xor(a6, 16); a6 += __shfl_xor(a6, 32);
    a7 += __shfl_xor(a7, 16); a7 += __shfl_xor(a7, 32);
    if (q == 0) {
        bf16x8 pk;
        pk[0] = (bf16)a0; pk[1] = (bf16)a1; pk[2] = (bf16)a2; pk[3] = (bf16)a3;
        pk[4] = (bf16)a4; pk[5] = (bf16)a5; pk[6] = (bf16)a6; pk[7] = (bf16)a7;
        *(bf16x8*)(aggb + (size_t)n * FF + 8 * cl) = pk;
    }
}

// -------- update: 128 nodes/block, 8 waves, half-sB double-pass GEMMs --------
// Phase count per block unchanged but block count halves; agg staged via
// wave-coalesced LDS path (wave-private sT rows, no extra barriers).
__global__ __launch_bounds__(512) void update_kernel(const bf16* __restrict__ aggb,
                                                     const bf16* __restrict__ c2t,
                                                     const float* __restrict__ c2b,
                                                     const bf16* __restrict__ ilt,
                                                     const float* __restrict__ ilb,
                                                     bf16* __restrict__ hb,
                                                     const bf16* __restrict__ c1n,
                                                     bf16* __restrict__ xf_out,
                                                     const bf16* __restrict__ l1t,
                                                     const float* __restrict__ l1b,
                                                     const bf16* __restrict__ l2t,
                                                     const float* __restrict__ l2b,
                                                     float* __restrict__ partial) {
    __shared__ bf16 sB[64 * 136];    // half-weight tile (restaged per pass)
    __shared__ bf16 sT[128 * 136];   // agg -> ssp(v) -> h_new (wave-private rows)
    int tid = threadIdx.x;
    int w = tid >> 6, lane = tid & 63, ln = lane & 15, kg = lane >> 4;
    int rowt = blockIdx.x * 128 + w * 16;
    int nrow = rowt + ln;                 // this thread's node (transposed layout)
    int arow = min(nrow, NN - 1);
    bool rowok = nrow < NN;
    // residual h prefetch (scattered 8B, issued early to hide LLC latency)
    bf16x4 hpre[8];
#pragma unroll
    for (int t = 0; t < 8; t++)
        hpre[t] = *(const bf16x4*)(hb + (size_t)arow * HH + t * 16 + kg * 4);
    // wave-coalesced agg stage: 16 rows x 256B = 4KB contiguous, 64B/lane
    {
        int srow = min(rowt + (lane >> 2), NN - 1);
        const bf16* src = aggb + (size_t)srow * FF + (lane & 3) * 32;
        bf16* dstp = &sT[(w * 16 + (lane >> 2)) * 136 + (lane & 3) * 32];
#pragma unroll
        for (int j = 0; j < 4; j++)
            *(bf16x8*)(dstp + j * 8) = *(const bf16x8*)(src + j * 8);
    }
    // GEMM1 (Ct): out[feat][node] = conv2^T @ agg^T  (operand-swapped MFMA)
    f32x4 acc[8] = {};
    bf16x8 breg[4];
#pragma unroll
    for (int h = 0; h < 2; h++) {
        if (h) __syncthreads();           // sB h=0 readers done
        for (int idx = tid * 8; idx < 64 * 128; idx += 4096)
            *(bf16x8*)&sB[(idx >> 7) * 136 + (idx & 127)] =
                *(const bf16x8*)(c2t + h * 64 * 128 + idx);
        __syncthreads();                  // also orders agg sT writes before breg reads
        if (h == 0) {
#pragma unroll
            for (int k0 = 0; k0 < 4; k0++)
                breg[k0] = *(const bf16x8*)&sT[(w * 16 + ln) * 136 + k0 * 32 + kg * 8];
        }
#pragma unroll
        for (int k0 = 0; k0 < 128; k0 += 32) {
#pragma unroll
            for (int t = 0; t < 4; t++) {
                bf16x8 afrag = *(const bf16x8*)&sB[(t * 16 + ln) * 136 + k0 + kg * 8];
                acc[h * 4 + t] = mfma16(afrag, breg[k0 >> 5], acc[h * 4 + t]);
            }
        }
    }
    // epilogue1: own sT rows (in-wave order; breg already in registers)
#pragma unroll
    for (int t = 0; t < 8; t++) {
        f32x4 bb = *(const f32x4*)(c2b + t * 16 + kg * 4);
        bf16x4 pk;
#pragma unroll
        for (int r = 0; r < 4; r++) pk[r] = (bf16)sspf(acc[t][r] + bb[r]);
        *(bf16x4*)&sT[(w * 16 + ln) * 136 + t * 16 + kg * 4] = pk;
    }
    // GEMM2: int_lin
    f32x4 acc2[8] = {};
    bf16x8 breg2[4];
#pragma unroll
    for (int h = 0; h < 2; h++) {
        __syncthreads();
        for (int idx = tid * 8; idx < 64 * 128; idx += 4096)
            *(bf16x8*)&sB[(idx >> 7) * 136 + (idx & 127)] =
                *(const bf16x8*)(ilt + h * 64 * 128 + idx);
        __syncthreads();
        if (h == 0) {
#pragma unroll
            for (int k0 = 0; k0 < 4; k0++)
                breg2[k0] = *(const bf16x8*)&sT[(w * 16 + ln) * 136 + k0 * 32 + kg * 8];
        }
#pragma unroll
        for (int k0 = 0; k0 < 128; k0 += 32) {
#pragma unroll
            for (int t = 0; t < 4; t++) {
                bf16x8 afrag = *(const bf16x8*)&sB[(t * 16 + ln) * 136 + k0 + kg * 8];
                acc2[h * 4 + t] = mfma16(afrag, breg2[k0 >> 5], acc2[h * 4 + t]);
            }
        }
    }
    bool is_last = (c1n == nullptr);
    // epilogue2: residual add; own sT rows
#pragma unroll
    for (int t = 0; t < 8; t++) {
        f32x4 bb = *(const f32x4*)(ilb + t * 16 + kg * 4);
        bf16x4 pk;
#pragma unroll
        for (int r = 0; r < 4; r++)
            pk[r] = (bf16)((float)hpre[t][r] + acc2[t][r] + bb[r]);
        if (rowok && !is_last) *(bf16x4*)(hb + (size_t)nrow * HH + t * 16 + kg * 4) = pk;
        *(bf16x4*)&sT[(w * 16 + ln) * 136 + t * 16 + kg * 4] = pk;
    }
    if (!is_last) {
        // fused next-layer xf = h_new @ conv1_next (same transposed form)
        f32x4 acc3[8] = {};
        bf16x8 breg3[4];
#pragma unroll
        for (int h = 0; h < 2; h++) {
            __syncthreads();
            for (int idx = tid * 8; idx < 64 * 128; idx += 4096)
                *(bf16x8*)&sB[(idx >> 7) * 136 + (idx & 127)] =
                    *(const bf16x8*)(c1n + h * 64 * 128 + idx);
            __syncthreads();
            if (h == 0) {
#pragma unroll
                for (int k0 = 0; k0 < 4; k0++)
                    breg3[k0] = *(const bf16x8*)&sT[(w * 16 + ln) * 136 + k0 * 32 + kg * 8];
            }
#pragma unroll
            for (int k0 = 0; k0 < 128; k0 += 32) {
#pragma unroll
                for (int t = 0; t < 4; t++) {
                    bf16x8 afrag = *(const bf16x8*)&sB[(t * 16 + ln) * 136 + k0 + kg * 8];
                    acc3[h * 4 + t] = mfma16(afrag, breg3[k0 >> 5], acc3[h * 4 + t]);
                }
            }
        }
#pragma unroll
        for (int t = 0; t < 8; t++) {
            bf16x4 pk;
#pragma unroll
            for (int r = 0; r < 4; r++) pk[r] = (bf16)acc3[t][r];
            if (rowok) *(bf16x4*)(xf_out + (size_t)nrow * FF + t * 16 + kg * 4) = pk;
        }
    } else {
        // fused head: ssp(h@lin1+b)@lin2+b, per-block partial sum (runs once)
        __syncthreads();
        for (int idx = tid * 8; idx < 64 * 128; idx += 4096)
            *(bf16x8*)&sB[(idx >> 7) * 136 + (idx & 127)] = *(const bf16x8*)(l1t + idx);
        __syncthreads();
        f32x4 acch[4] = {};
#pragma unroll
        for (int k0 = 0; k0 < 128; k0 += 32) {
            bf16x8 a = *(const bf16x8*)&sT[(w * 16 + ln) * 136 + k0 + kg * 8];
#pragma unroll
            for (int t = 0; t < 4; t++) {
                bf16x8 b = *(const bf16x8*)&sB[(t * 16 + ln) * 136 + k0 + kg * 8];
                acch[t] = mfma16(a, b, acch[t]);
            }
        }
#pragma unroll
        for (int t = 0; t < 4; t++) {
            int colt = t * 16 + ln;
            float bb = l1b[colt];
#pragma unroll
            for (int r = 0; r < 4; r++)
                sT[(w * 16 + kg * 4 + r) * 136 + colt] = (bf16)sspf(acch[t][r] + bb);
        }
        __syncthreads();
        for (int idx = tid * 8; idx < 64 * 64; idx += 4096) {
            int n = idx >> 6, k = idx & 63;
            *(bf16x8*)&sB[n * 136 + k] = *(const bf16x8*)(l2t + idx);
        }
        __syncthreads();
        f32x4 acc2h[4] = {};
#pragma unroll
        for (int k0 = 0; k0 < 64; k0 += 32) {
            bf16x8 a = *(const bf16x8*)&sT[(w * 16 + ln) * 136 + k0 + kg * 8];
#pragma unroll
            for (int t = 0; t < 4; t++) {
                bf16x8 b = *(const bf16x8*)&sB[(t * 16 + ln) * 136 + k0 + kg * 8];
                acc2h[t] = mfma16(a, b, acc2h[t]);
            }
        }
        __syncthreads();   // all sT reads done; reuse as f32 scratch
        float* sPart = (float*)sT;
#pragma unroll
        for (int t = 0; t < 4; t++) {
            int colt = t * 16 + ln;
            float bb = l2b[colt];
            float v = 0.f;
#pragma unroll
            for (int r = 0; r < 4; r++) {
                int orow = rowt + kg * 4 + r;
                if (orow < NN) v += acc2h[t][r] + bb;
            }
            v += __shfl_xor(v, 16);
            v += __shfl_xor(v, 32);
            if (kg == 0) sPart[w * 64 + colt] = v;
        }
        __syncthreads();
        if (tid < 64) {
            float s = 0.f;
#pragma unroll
            for (int ww = 0; ww < 8; ww++) s += sPart[ww * 64 + tid];
            partial[blockIdx.x * 64 + tid] = s;
        }
    }
}

// -------- finalA: one block per column, parallel reduce over 391 partials ----
__global__ __launch_bounds__(256) void finalA_kernel(const float* __restrict__ partial,
                                                     float* __restrict__ colsum) {
    __shared__ float red[256];
    int c = blockIdx.x, t = threadIdx.x;
    float s = 0.f;
    for (int b = t; b < NB2; b += 256) s += partial[b * 64 + c];
    red[t] = s;
    __syncthreads();
    for (int off = 128; off > 0; off >>= 1) {
        if (t < off) red[t] += red[t + off];
        __syncthreads();
    }
    if (t == 0) colsum[c] = red[0];
}

// -------- finalB: readout GEMV (64x12, trivial) ------------------------------
__global__ __launch_bounds__(64) void finalB_kernel(const float* __restrict__ colsum,
                                                    const float* __restrict__ rw,
                                                    const float* __restrict__ rb,
                                                    float* __restrict__ out) {
    __shared__ float sv[64];
    int j = threadIdx.x;
    sv[j] = colsum[j];
    __syncthreads();
    if (j < OUT_DIM) {
        float o = rb[j];
        for (int i = 0; i < H2D; i++) o += sv[i] * rw[i * OUT_DIM + j];
        out[j] = o;
    }
}

// -------- launch -------------------------------------------------------------
extern "C" void kernel_launch(void* const* d_in, const int* in_sizes, int n_in,
                              void* d_out, int out_size, void* d_ws, size_t ws_size,
                              hipStream_t stream) {
    const int*   x_atoms    = (const int*)d_in[0];
    const int*   edge_index = (const int*)d_in[1];
    const float* edge_attr  = (const float*)d_in[2];
    const float* embedding  = (const float*)d_in[3];
    const float* mlp_w1     = (const float*)d_in[4];
    const float* mlp_b1     = (const float*)d_in[5];
    const float* mlp_w2     = (const float*)d_in[6];
    const float* mlp_b2     = (const float*)d_in[7];
    const float* conv1_w    = (const float*)d_in[8];
    const float* conv2_w    = (const float*)d_in[9];
    const float* conv2_b    = (const float*)d_in[10];
    const float* int_lin_w  = (const float*)d_in[11];
    const float* int_lin_b  = (const float*)d_in[12];
    const float* lin1_w     = (const float*)d_in[13];
    const float* lin1_b     = (const float*)d_in[14];
    const float* lin2_w     = (const float*)d_in[15];
    const float* lin2_b     = (const float*)d_in[16];
    const float* readout_w  = (const float*)d_in[17];
    const float* readout_b  = (const float*)d_in[18];

    char* ws = (char*)d_ws;
    bf16*  hb      = (bf16*)(ws + 0);              // 12,800,000
    bf16*  xfA     = (bf16*)(ws + 12800000);       // 12,800,000
    bf16*  xfB     = (bf16*)(ws + 25600000);       // 12,800,000
    bf16*  aggb    = (bf16*)(ws + 38400000);       // 12,800,000
    float* partial = (float*)(ws + 51200000);      // 200,192
    size_t wb = 51400192;
    bf16* c1t = (bf16*)(ws + wb);                  // 196,608
    bf16* c2t = (bf16*)(ws + wb + 196608);
    bf16* ilt = (bf16*)(ws + wb + 393216);
    bf16* w1t = (bf16*)(ws + wb + 589824);         // 98,304
    bf16* w2t = (bf16*)(ws + wb + 688128);         // 196,608
    bf16* l1t = (bf16*)(ws + wb + 884736);         // 16,384
    bf16* l2t = (bf16*)(ws + wb + 901120);         // 8,192 -> ends 52,309,504
    int*   d_hist = (int*)(ws + 52309504);         // 200,000
    int*   d_rs   = (int*)(ws + 52509504);         // 200,000
    int*   d_bcur = (int*)(ws + 52709504);         // 1,024 (bucket_cur)
    int*   d_bsum = (int*)(ws + 52710528);         // 1,024
    int*   d_es   = (int*)(ws + 52711552);         // 3,200,000 -> 55,911,552
    bf16*  tab    = (bf16*)(ws + 55911552);        // 6*4097*128*2 = 6,292,992 -> 62,204,544
    int2*  d_tmp8 = (int2*)(ws + 62204544);        // 6,400,000 -> 68,604,544
    float* colsum = (float*)(ws + 68604544);       // 256 -> 68,604,800

    PrepArgs pa = { conv1_w, conv2_w, int_lin_w, mlp_w1, mlp_w2, lin1_w, lin2_w,
                    c1t, c2t, ilt, w1t, w2t, l1t, l2t, d_hist };
    prep_kernel<<<32, 256, 0, stream>>>(pa);
    table_kernel<<<LL * 65, 256, 0, stream>>>(w1t, w2t, mlp_b1, mlp_b2, tab);

    // sort edges by dst (once; graph static across layers)
    hist_kernel<<<(EE + 255) / 256, 256, 0, stream>>>(edge_index, d_hist);
    scanA_kernel<<<SB, 256, 0, stream>>>(d_hist, d_bsum);
    scanC_kernel<<<SB, 256, 0, stream>>>(d_hist, d_bsum, d_rs, d_bcur);
    scat1_kernel<<<NBUK, 256, 0, stream>>>(edge_attr, edge_index, d_bcur, d_tmp8);
    scat2_kernel<<<NBUK, 256, 0, stream>>>(d_rs, d_tmp8, d_es);

    xf0_kernel<<<NBLK, 256, 0, stream>>>(x_atoms, embedding, c1t, hb, xfA);
    bf16* xf_in = xfA;
    bf16* xf_out = xfB;
    for (int l = 0; l < LL; l++) {
        edge_kernel<<<NN / 4, 256, 0, stream>>>(d_es, d_rs, d_hist, xf_in,
                                                tab + (size_t)l * (NK + 1) * FF, aggb);
        const bf16* c1n = (l + 1 < LL) ? (c1t + (size_t)(l + 1) * FF * HH) : nullptr;
        update_kernel<<<NB2, 512, 0, stream>>>(aggb, c2t + (size_t)l * HH * FF,
                                               conv2_b + l * HH,
                                               ilt + (size_t)l * HH * HH, int_lin_b + l * HH,
                                               hb, c1n, xf_out,
                                               l1t, lin1_b, l2t, lin2_b, partial);
        bf16* tmp = xf_in; xf_in = xf_out; xf_out = tmp;
    }
    finalA_kernel<<<64, 256, 0, stream>>>(partial, colsum);
    finalB_kernel<<<1, 64, 0, stream>>>(colsum, readout_w, readout_b, (float*)d_out);
}